// Round 12
// baseline (413.290 us; speedup 1.0000x reference)
//
#include <hip/hip_runtime.h>
#include <hip/hip_bf16.h>

#define NNODES 50000
#define NEDGES 600000
#define NGRAPHS 512
#define BN_EPS 1e-5f

typedef short bf16x8 __attribute__((ext_vector_type(8)));
typedef float f32x4 __attribute__((ext_vector_type(4)));

// split fp32 -> hi/lo bf16 (RNE); hi+lo carries ~16 mantissa bits
__device__ __forceinline__ void bf_split(float x, ushort& h, ushort& l) {
    __hip_bfloat16 bh = __float2bfloat16(x);
    float r = x - __bfloat162float(bh);
    __hip_bfloat16 bl = __float2bfloat16(r);
    h = __builtin_bit_cast(ushort, bh);
    l = __builtin_bit_cast(ushort, bl);
}
__device__ __forceinline__ ushort f2b(float x) {
    return __builtin_bit_cast(ushort, __float2bfloat16(x));
}
__device__ __forceinline__ float b2f(ushort u) {
    union { uint i; float f; } c; c.i = ((uint)u) << 16; return c.f;
}

// ------------------------------------------------------------------- prep
// One dispatch: x->bf16 (blocks 0..3124), zero pooled (3125..3316), zero
// counts (3317..3512), wsplit 6 matrices (3513..3608), row_ptr[N] init.
__global__ __launch_bounds__(256) void prep_kernel(
    const float* __restrict__ x, ushort* __restrict__ xh,
    float* __restrict__ pooled, int* __restrict__ counts, int* __restrict__ row_ptr,
    const float* W0, const float* W1, const float* W2, const float* W3,
    const float* W4, const float* W5, ushort* __restrict__ hi, ushort* __restrict__ lo) {
    int b = blockIdx.x, t = threadIdx.x;
    if (b < 3125) {                                 // x: 6.4M floats -> bf16
        int f4 = b * 512 + t * 2;
        float4 a0 = ((const float4*)x)[f4];
        float4 a1 = ((const float4*)x)[f4 + 1];
        ushort4 u0 = {f2b(a0.x), f2b(a0.y), f2b(a0.z), f2b(a0.w)};
        ushort4 u1 = {f2b(a1.x), f2b(a1.y), f2b(a1.z), f2b(a1.w)};
        int e0 = f4 * 4;
        *(ushort4*)(xh + e0) = u0;
        *(ushort4*)(xh + e0 + 4) = u1;
        if (b == 0 && t == 0) row_ptr[NNODES] = NEDGES;
    } else if (b < 3317) {                          // pooled: 512*384 floats
        ((float4*)pooled)[(b - 3125) * 256 + t] = make_float4(0.f, 0.f, 0.f, 0.f);
    } else if (b < 3513) {                          // counts: 50000 ints
        int i = (b - 3317) * 256 + t;
        if (i < NNODES) counts[i] = 0;
    } else {                                        // wsplit: 96 blocks
        int wb = b - 3513;
        const float* Ws[6] = {W0, W1, W2, W3, W4, W5};
        const float* W = Ws[wb >> 4];
        ushort* h = hi + (size_t)(wb >> 4) * 16384;
        ushort* l = lo + (size_t)(wb >> 4) * 16384;
        int chunk = wb & 15;
#pragma unroll
        for (int i = 0; i < 4; i++) {
            int idx = chunk * 1024 + i * 256 + t;
            int n = idx >> 7, k = idx & 127;
            ushort hh, ll;
            bf_split(W[k * 128 + n], hh, ll);
            h[n * 128 + k] = hh;
            l[n * 128 + k] = ll;
        }
    }
}

// ---------------------------------------------------------------- CSR build
__global__ __launch_bounds__(256) void hist_kernel(const int* __restrict__ dst,
                                                   int* __restrict__ counts, int E) {
    int i = blockIdx.x * 256 + threadIdx.x;
    if (i < E) atomicAdd(&counts[dst[i]], 1);
}

__global__ __launch_bounds__(256) void scan1_kernel(const int* __restrict__ counts,
                                                    int* __restrict__ partials, int n) {
    __shared__ int s[256];
    int i = blockIdx.x * 256 + threadIdx.x;
    int v = (i < n) ? counts[i] : 0;
    s[threadIdx.x] = v;
    __syncthreads();
    for (int off = 128; off > 0; off >>= 1) {
        if (threadIdx.x < off) s[threadIdx.x] += s[threadIdx.x + off];
        __syncthreads();
    }
    if (threadIdx.x == 0) partials[blockIdx.x] = s[0];
}

// scan3 with inline base reduction (no scan2 dispatch), nb<=256
__global__ __launch_bounds__(256) void scan3_kernel(const int* __restrict__ counts,
                                                    const int* __restrict__ partials,
                                                    int* __restrict__ row_ptr,
                                                    int* __restrict__ cursor, int n, int nb) {
    __shared__ int s[256];
    __shared__ int base_sh;
    int t = threadIdx.x;
    int pv = (t < (int)blockIdx.x && t < nb) ? partials[t] : 0;
    s[t] = pv;
    __syncthreads();
    for (int off = 128; off > 0; off >>= 1) {
        if (t < off) s[t] += s[t + off];
        __syncthreads();
    }
    if (t == 0) base_sh = s[0];
    __syncthreads();
    int base = base_sh;
    int i = blockIdx.x * 256 + t;
    int v = (i < n) ? counts[i] : 0;
    __syncthreads();
    s[t] = v;
    __syncthreads();
    for (int off = 1; off < 256; off <<= 1) {
        int nv = (t >= off) ? s[t - off] : 0;
        __syncthreads();
        s[t] += nv;
        __syncthreads();
    }
    if (i < n) {
        int ex = base + s[t] - v;   // exclusive
        row_ptr[i] = ex;
        cursor[i] = ex;
    }
}

__global__ __launch_bounds__(256) void scatter_kernel(const int* __restrict__ src,
                                                      const int* __restrict__ dst,
                                                      int* __restrict__ cursor,
                                                      int* __restrict__ esrc, int E) {
    int i = blockIdx.x * 256 + threadIdx.x;
    if (i < E) {
        int p = atomicAdd(&cursor[dst[i]], 1);
        esrc[p] = src[i];
    }
}

// ------------------------------------------------------------- aggregation
// (R10/R11-proven ~30us) 2 nodes/wave, 32 lanes x 4 ch. Neighbors from bf16
// hi-plane (256B rows); self exact (fp32 x or hi+lo). fp32 accumulate ->
// exact-sum hi/lo split out.
template <bool SELF_F32>
__global__ __launch_bounds__(256) void agg_kernel(
    const float* __restrict__ xf,
    const ushort* __restrict__ phi, const ushort* __restrict__ plo,
    const int* __restrict__ rp, const int* __restrict__ esrc,
    ushort* __restrict__ ohi, ushort* __restrict__ olo, int n) {
    int wid  = (blockIdx.x * 256 + threadIdx.x) >> 6;
    int lane = threadIdx.x & 63;
    int node = wid * 2 + (lane >> 5);
    int q = lane & 31;
    if (node >= n) return;
    const ushort4* xh = (const ushort4*)phi;
    float4 acc;
    if (SELF_F32) {
        acc = ((const float4*)xf)[(size_t)node * 32 + q];
    } else {
        ushort4 sh = xh[(size_t)node * 32 + q];
        ushort4 sl = ((const ushort4*)plo)[(size_t)node * 32 + q];
        acc.x = b2f(sh.x) + b2f(sl.x);
        acc.y = b2f(sh.y) + b2f(sl.y);
        acc.z = b2f(sh.z) + b2f(sl.z);
        acc.w = b2f(sh.w) + b2f(sl.w);
    }
    int beg = rp[node], end = rp[node + 1];
    int e = beg;
    for (; e + 8 <= end; e += 8) {
        int i0 = esrc[e],     i1 = esrc[e + 1], i2 = esrc[e + 2], i3 = esrc[e + 3];
        int i4 = esrc[e + 4], i5 = esrc[e + 5], i6 = esrc[e + 6], i7 = esrc[e + 7];
        ushort4 v0 = xh[(size_t)i0 * 32 + q];
        ushort4 v1 = xh[(size_t)i1 * 32 + q];
        ushort4 v2 = xh[(size_t)i2 * 32 + q];
        ushort4 v3 = xh[(size_t)i3 * 32 + q];
        ushort4 v4 = xh[(size_t)i4 * 32 + q];
        ushort4 v5 = xh[(size_t)i5 * 32 + q];
        ushort4 v6 = xh[(size_t)i6 * 32 + q];
        ushort4 v7 = xh[(size_t)i7 * 32 + q];
        acc.x += ((b2f(v0.x) + b2f(v1.x)) + (b2f(v2.x) + b2f(v3.x))) +
                 ((b2f(v4.x) + b2f(v5.x)) + (b2f(v6.x) + b2f(v7.x)));
        acc.y += ((b2f(v0.y) + b2f(v1.y)) + (b2f(v2.y) + b2f(v3.y))) +
                 ((b2f(v4.y) + b2f(v5.y)) + (b2f(v6.y) + b2f(v7.y)));
        acc.z += ((b2f(v0.z) + b2f(v1.z)) + (b2f(v2.z) + b2f(v3.z))) +
                 ((b2f(v4.z) + b2f(v5.z)) + (b2f(v6.z) + b2f(v7.z)));
        acc.w += ((b2f(v0.w) + b2f(v1.w)) + (b2f(v2.w) + b2f(v3.w))) +
                 ((b2f(v4.w) + b2f(v5.w)) + (b2f(v6.w) + b2f(v7.w)));
    }
    for (; e + 2 <= end; e += 2) {
        int i0 = esrc[e], i1 = esrc[e + 1];
        ushort4 v0 = xh[(size_t)i0 * 32 + q];
        ushort4 v1 = xh[(size_t)i1 * 32 + q];
        acc.x += b2f(v0.x) + b2f(v1.x); acc.y += b2f(v0.y) + b2f(v1.y);
        acc.z += b2f(v0.z) + b2f(v1.z); acc.w += b2f(v0.w) + b2f(v1.w);
    }
    for (; e < end; e++) {
        ushort4 v = xh[(size_t)esrc[e] * 32 + q];
        acc.x += b2f(v.x); acc.y += b2f(v.y); acc.z += b2f(v.z); acc.w += b2f(v.w);
    }
    ushort4 hh, ll;
    bf_split(acc.x, hh.x, ll.x);
    bf_split(acc.y, hh.y, ll.y);
    bf_split(acc.z, hh.z, ll.z);
    bf_split(acc.w, hh.w, ll.w);
    *(ushort4*)(ohi + (size_t)node * 128 + q * 4) = hh;
    *(ushort4*)(olo + (size_t)node * 128 + q * 4) = ll;
}

// --------------------------------------------------------------- fused MLP
// C = act( BN_ReLU( A@W1 ) @ W2 ), 64-row tile (R11's 128-tile had 69.6KB
// LDS -> 1.53 blocks/CU grid balance; this is 35KB -> 4 blocks/CU, 782
// blocks). Wave tile 32x64 = 2x4 of 16x16x32. Mean-pool contribution fused
// into the epilogue (kills the pool dispatch + L3 plane round-trip):
// outputs staged to LDS fp32, per-column run-length reduce over the sorted
// batch ids, ~1.3 boundary atomicAdds per column-half.
template <bool RELU_OUT, bool WRITE_PLANES>
__global__ __launch_bounds__(256) void mlp_kernel(
    const ushort* __restrict__ Ahi, const ushort* __restrict__ Alo,
    const ushort* __restrict__ W1hi, const ushort* __restrict__ W1lo,
    const ushort* __restrict__ W2hi, const ushort* __restrict__ W2lo,
    const float* __restrict__ b1, const float* __restrict__ gm,
    const float* __restrict__ bt, const float* __restrict__ rm,
    const float* __restrict__ rv, const float* __restrict__ b2,
    ushort* __restrict__ Chi, ushort* __restrict__ Clo,
    const int* __restrict__ batch, float* __restrict__ pooled, int poff, int M) {
    __shared__ __align__(16) ushort smem[2 * 64 * 136];  // 34816 B
    __shared__ int bsm[64];
    // A dbuf view: first 8192 ushorts. buf b, plane p, off in [0,2048)
#define AS(b_, p_, o_) smem[(((b_) * 2 + (p_)) << 11) + (o_)]
    // H view: plane p, off = row*136 + col
#define HS(p_, o_) smem[(p_)*8704 + (o_)]
    const int t = threadIdx.x;
    const int lane = t & 63;
    const int wv = t >> 6;
    const int wr = wv >> 1, wc = wv & 1;   // 2x2 waves: 32 rows x 64 cols each
    const int row0 = blockIdx.x * 64;
    const int g = lane >> 4, c = lane & 15;

    if (t < 64) bsm[t] = (row0 + t < M) ? batch[row0 + t] : -1;

    // staging: 256 16B-segs per plane per kb; thread owns seg t
    const int m0 = t >> 2, k80 = (t & 3) * 8;
    int r0 = row0 + m0; if (r0 >= M) r0 = M - 1;
    const size_t ga0 = (size_t)r0 * 128 + k80;
    const int la0 = m0 * 32 + k80;

    f32x4 acc[2][4];
#pragma unroll
    for (int i = 0; i < 2; i++)
#pragma unroll
        for (int j = 0; j < 4; j++) acc[i][j] = (f32x4){0.f, 0.f, 0.f, 0.f};

    uint4 ph0 = *(const uint4*)(Ahi + ga0);
    uint4 pl0 = *(const uint4*)(Alo + ga0);
    *(uint4*)&AS(0, 0, la0) = ph0;
    *(uint4*)&AS(0, 1, la0) = pl0;
    __syncthreads();

    // ---------------- phase 1: A @ W1 (A dbuf in LDS, W frags from global)
    int cur = 0;
    for (int kb = 0; kb < 4; kb++) {
        bf16x8 bh[4], bl[4];
#pragma unroll
        for (int ct = 0; ct < 4; ct++) {
            const size_t wo = (size_t)(wc * 64 + ct * 16 + c) * 128 + kb * 32 + g * 8;
            bh[ct] = *(const bf16x8*)(W1hi + wo);
            bl[ct] = *(const bf16x8*)(W1lo + wo);
        }
        if (kb < 3) {
            const size_t o = (size_t)(kb + 1) * 32;
            ph0 = *(const uint4*)(Ahi + ga0 + o);
            pl0 = *(const uint4*)(Alo + ga0 + o);
        }
        bf16x8 ah[2], al[2];
#pragma unroll
        for (int rt = 0; rt < 2; rt++) {
            int off = (wr * 32 + rt * 16 + c) * 32 + g * 8;
            ah[rt] = *(bf16x8*)&AS(cur, 0, off);
            al[rt] = *(bf16x8*)&AS(cur, 1, off);
        }
#pragma unroll
        for (int rt = 0; rt < 2; rt++)
#pragma unroll
            for (int ct = 0; ct < 4; ct++) {
                acc[rt][ct] = __builtin_amdgcn_mfma_f32_16x16x32_bf16(ah[rt], bh[ct], acc[rt][ct], 0, 0, 0);
                acc[rt][ct] = __builtin_amdgcn_mfma_f32_16x16x32_bf16(ah[rt], bl[ct], acc[rt][ct], 0, 0, 0);
                acc[rt][ct] = __builtin_amdgcn_mfma_f32_16x16x32_bf16(al[rt], bh[ct], acc[rt][ct], 0, 0, 0);
            }
        if (kb < 3) {
            *(uint4*)&AS(cur ^ 1, 0, la0) = ph0;
            *(uint4*)&AS(cur ^ 1, 1, la0) = pl0;
        }
        __syncthreads();   // final iter: all A reads done -> H may overwrite
        cur ^= 1;
    }

    // ---------------- BN + ReLU -> H (hi/lo bf16) in LDS
    {
#pragma unroll
        for (int ct = 0; ct < 4; ct++) {
            int n = wc * 64 + ct * 16 + c;
            float s = gm[n] * rsqrtf(rv[n] + BN_EPS);
            float ca = (b1[n] - rm[n]) * s + bt[n];
#pragma unroll
            for (int rt = 0; rt < 2; rt++)
#pragma unroll
                for (int r = 0; r < 4; r++) {
                    int row = wr * 32 + rt * 16 + g * 4 + r;
                    float v = fmaxf(acc[rt][ct][r] * s + ca, 0.f);
                    ushort hh, ll;
                    bf_split(v, hh, ll);
                    HS(0, row * 136 + n) = hh;
                    HS(1, row * 136 + n) = ll;
                }
        }
    }
    __syncthreads();

    // ---------------- phase 2: H @ W2
#pragma unroll
    for (int i = 0; i < 2; i++)
#pragma unroll
        for (int j = 0; j < 4; j++) acc[i][j] = (f32x4){0.f, 0.f, 0.f, 0.f};

#pragma unroll
    for (int kb = 0; kb < 4; kb++) {
        bf16x8 bh[4], bl[4];
#pragma unroll
        for (int ct = 0; ct < 4; ct++) {
            const size_t wo = (size_t)(wc * 64 + ct * 16 + c) * 128 + kb * 32 + g * 8;
            bh[ct] = *(const bf16x8*)(W2hi + wo);
            bl[ct] = *(const bf16x8*)(W2lo + wo);
        }
        bf16x8 ah[2], al[2];
#pragma unroll
        for (int rt = 0; rt < 2; rt++) {
            int off = (wr * 32 + rt * 16 + c) * 136 + kb * 32 + g * 8;
            ah[rt] = *(bf16x8*)&HS(0, off);
            al[rt] = *(bf16x8*)&HS(1, off);
        }
#pragma unroll
        for (int rt = 0; rt < 2; rt++)
#pragma unroll
            for (int ct = 0; ct < 4; ct++) {
                acc[rt][ct] = __builtin_amdgcn_mfma_f32_16x16x32_bf16(ah[rt], bh[ct], acc[rt][ct], 0, 0, 0);
                acc[rt][ct] = __builtin_amdgcn_mfma_f32_16x16x32_bf16(ah[rt], bl[ct], acc[rt][ct], 0, 0, 0);
                acc[rt][ct] = __builtin_amdgcn_mfma_f32_16x16x32_bf16(al[rt], bh[ct], acc[rt][ct], 0, 0, 0);
            }
    }
    __syncthreads();   // all H reads done -> P may overwrite smem

    // ---------------- epilogue: +b2 (,ReLU) -> planes + LDS P for pooling
    float* P = (float*)smem;   // [64][132] fp32 = 33792B
    {
        float ca2[4];
#pragma unroll
        for (int ct = 0; ct < 4; ct++) ca2[ct] = b2[wc * 64 + ct * 16 + c];
#pragma unroll
        for (int rt = 0; rt < 2; rt++)
#pragma unroll
            for (int r = 0; r < 4; r++) {
                int rl = wr * 32 + rt * 16 + g * 4 + r;
                int row = row0 + rl;
                bool valid = row < M;
#pragma unroll
                for (int ct = 0; ct < 4; ct++) {
                    int col = wc * 64 + ct * 16 + c;
                    float v = acc[rt][ct][r] + ca2[ct];
                    if (RELU_OUT) v = fmaxf(v, 0.f);
                    P[rl * 132 + col] = valid ? v : 0.f;
                    if (WRITE_PLANES && valid) {
                        ushort hh, ll;
                        bf_split(v, hh, ll);
                        Chi[(size_t)row * 128 + col] = hh;
                        Clo[(size_t)row * 128 + col] = ll;
                    }
                }
            }
    }
    __syncthreads();

    // ---------------- fused mean-pool contribution (batch is sorted)
    {
        int col = t & 127;
        int rbase = (t >> 7) * 32;   // rows 0..31 or 32..63
        int gcur = bsm[rbase];
        float accp = 0.f;
#pragma unroll 8
        for (int r = 0; r < 32; r++) {
            int gg = bsm[rbase + r];
            if (gg != gcur) {        // wave-uniform branch (sorted batch)
                if (gcur >= 0) atomicAdd(&pooled[gcur * 384 + poff + col], accp);
                accp = 0.f;
                gcur = gg;
            }
            accp += P[(rbase + r) * 132 + col];
        }
        if (gcur >= 0) atomicAdd(&pooled[gcur * 384 + poff + col], accp);
    }
#undef AS
#undef HS
}

// ------------------------------------------------------------------- final
__global__ __launch_bounds__(128) void final_kernel(const float* __restrict__ pooled,
                                                    const int* __restrict__ batch,
                                                    const float* __restrict__ W,
                                                    const float* __restrict__ b,
                                                    float* __restrict__ out, int n) {
    __shared__ float ps[384];
    int gph = blockIdx.x, t = threadIdx.x;
    int lo1 = 0, hi1 = n;
    while (lo1 < hi1) { int mid = (lo1 + hi1) >> 1; if (batch[mid] < gph) lo1 = mid + 1; else hi1 = mid; }
    int start = lo1;
    int lo2 = start, hi2 = n;
    while (lo2 < hi2) { int mid = (lo2 + hi2) >> 1; if (batch[mid] < gph + 1) lo2 = mid + 1; else hi2 = mid; }
    int cnt = lo2 - start;
    float inv = 1.f / (float)(cnt > 0 ? cnt : 1);
    for (int i = t; i < 384; i += 128) ps[i] = pooled[gph * 384 + i] * inv;
    __syncthreads();
    float acc = b[t];
#pragma unroll 8
    for (int k = 0; k < 384; k++) acc += ps[k] * W[k * 128 + t];
    out[gph * 128 + t] = acc;
}

// ------------------------------------------------------------------ launch
extern "C" void kernel_launch(void* const* d_in, const int* in_sizes, int n_in,
                              void* d_out, int out_size, void* d_ws, size_t ws_size,
                              hipStream_t stream) {
    const float* x     = (const float*)d_in[0];
    const int*   edge  = (const int*)d_in[1];
    const int*   batch = (const int*)d_in[2];
    const float* p[32];
    for (int i = 0; i < n_in && i < 32; i++) p[i] = (const float*)d_in[i];
    const float* lin_W = p[27];
    const float* lin_b = p[28];

    char* w = (char*)d_ws;
    auto alloc = [&](size_t bytes) { void* r = (void*)w; w += (bytes + 255) & ~(size_t)255; return r; };
    const size_t PL = (size_t)NNODES * 128;
    ushort* thi   = (ushort*)alloc(PL * 2);   // agg out planes
    ushort* tlo   = (ushort*)alloc(PL * 2);
    ushort* xh0   = (ushort*)alloc(PL * 2);   // bf16(x); dead after agg L1
    ushort* p1h   = (ushort*)alloc(PL * 2);
    ushort* p1l   = (ushort*)alloc(PL * 2);
    ushort* p2h   = xh0;                      // alias: xh0 dead before mlp L2 writes
    ushort* p2l   = (ushort*)alloc(PL * 2);
    float* pooled = (float*)alloc((size_t)NGRAPHS * 384 * 4);
    int* counts   = (int*)alloc((size_t)NNODES * 4);
    int* cursor   = (int*)alloc((size_t)NNODES * 4);
    int* row_ptr  = (int*)alloc((size_t)(NNODES + 1) * 4);
    int* esrc     = (int*)alloc((size_t)NEDGES * 4);
    int* partials = (int*)alloc(256 * 4);
    ushort* wt_hi = (ushort*)alloc((size_t)6 * 16384 * 2);
    ushort* wt_lo = (ushort*)alloc((size_t)6 * 16384 * 2);

    const int* src = edge;
    const int* dst = edge + NEDGES;

    // --- prep: x->bf16, zero pooled/counts, row_ptr[N], wsplit (1 dispatch)
    prep_kernel<<<3609, 256, 0, stream>>>(x, xh0, pooled, counts, row_ptr,
                                          p[3], p[9], p[11], p[17], p[19], p[25],
                                          wt_hi, wt_lo);

    // --- CSR build: 4 dispatches
    int nb = (NNODES + 255) / 256;  // 196
    hist_kernel<<<(NEDGES + 255) / 256, 256, 0, stream>>>(dst, counts, NEDGES);
    scan1_kernel<<<nb, 256, 0, stream>>>(counts, partials, NNODES);
    scan3_kernel<<<nb, 256, 0, stream>>>(counts, partials, row_ptr, cursor, NNODES, nb);
    scatter_kernel<<<(NEDGES + 255) / 256, 256, 0, stream>>>(src, dst, cursor, esrc, NEDGES);

    // --- 3 GIN layers (mlp fuses the mean-pool contribution)
    int mlp_grid = (NNODES + 63) / 64;              // 782
    int agg_grid = (NNODES / 2 * 64 + 255) / 256;   // 6250

    // layer 1: self fp32 x, neighbors xh0
    agg_kernel<true><<<agg_grid, 256, 0, stream>>>(x, xh0, nullptr, row_ptr, esrc,
                                                   thi, tlo, NNODES);
    mlp_kernel<true, true><<<mlp_grid, 256, 0, stream>>>(thi, tlo,
        wt_hi + 0 * 16384, wt_lo + 0 * 16384, wt_hi + 1 * 16384, wt_lo + 1 * 16384,
        p[4], p[5], p[6], p[7], p[8], p[10], p1h, p1l, batch, pooled, 0, NNODES);
    // layer 2
    agg_kernel<false><<<agg_grid, 256, 0, stream>>>(nullptr, p1h, p1l, row_ptr, esrc,
                                                    thi, tlo, NNODES);
    mlp_kernel<true, true><<<mlp_grid, 256, 0, stream>>>(thi, tlo,
        wt_hi + 2 * 16384, wt_lo + 2 * 16384, wt_hi + 3 * 16384, wt_lo + 3 * 16384,
        p[12], p[13], p[14], p[15], p[16], p[18], p2h, p2l, batch, pooled, 128, NNODES);
    // layer 3 (no relu, no plane writes — pool-only output)
    agg_kernel<false><<<agg_grid, 256, 0, stream>>>(nullptr, p2h, p2l, row_ptr, esrc,
                                                    thi, tlo, NNODES);
    mlp_kernel<false, false><<<mlp_grid, 256, 0, stream>>>(thi, tlo,
        wt_hi + 4 * 16384, wt_lo + 4 * 16384, wt_hi + 5 * 16384, wt_lo + 5 * 16384,
        p[20], p[21], p[22], p[23], p[24], p[26], nullptr, nullptr, batch, pooled, 256, NNODES);

    // --- final linear on mean-pooled JK-concat
    final_kernel<<<NGRAPHS, 128, 0, stream>>>(pooled, batch, lin_W, lin_b,
                                              (float*)d_out, NNODES);
}

// Round 13
// 381.039 us; speedup vs baseline: 1.0846x; 1.0846x over previous
//
#include <hip/hip_runtime.h>
#include <hip/hip_bf16.h>

#define NNODES 50000
#define NEDGES 600000
#define NGRAPHS 512
#define BN_EPS 1e-5f

typedef short bf16x8 __attribute__((ext_vector_type(8)));
typedef float f32x4 __attribute__((ext_vector_type(4)));

// split fp32 -> hi/lo bf16 (RNE); hi+lo carries ~16 mantissa bits
__device__ __forceinline__ void bf_split(float x, ushort& h, ushort& l) {
    __hip_bfloat16 bh = __float2bfloat16(x);
    float r = x - __bfloat162float(bh);
    __hip_bfloat16 bl = __float2bfloat16(r);
    h = __builtin_bit_cast(ushort, bh);
    l = __builtin_bit_cast(ushort, bl);
}
__device__ __forceinline__ ushort f2b(float x) {
    return __builtin_bit_cast(ushort, __float2bfloat16(x));
}
__device__ __forceinline__ float b2f(ushort u) {
    union { uint i; float f; } c; c.i = ((uint)u) << 16; return c.f;
}

// ------------------------------------------------------------------- prep
// One dispatch: x->bf16 (blocks 0..3124), zero pooled (3125..3316), zero
// counts (3317..3512), wsplit 6 matrices (3513..3608), row_ptr[N] init.
__global__ __launch_bounds__(256) void prep_kernel(
    const float* __restrict__ x, ushort* __restrict__ xh,
    float* __restrict__ pooled, int* __restrict__ counts, int* __restrict__ row_ptr,
    const float* W0, const float* W1, const float* W2, const float* W3,
    const float* W4, const float* W5, ushort* __restrict__ hi, ushort* __restrict__ lo) {
    int b = blockIdx.x, t = threadIdx.x;
    if (b < 3125) {                                 // x: 6.4M floats -> bf16
        int f4 = b * 512 + t * 2;
        float4 a0 = ((const float4*)x)[f4];
        float4 a1 = ((const float4*)x)[f4 + 1];
        ushort4 u0 = {f2b(a0.x), f2b(a0.y), f2b(a0.z), f2b(a0.w)};
        ushort4 u1 = {f2b(a1.x), f2b(a1.y), f2b(a1.z), f2b(a1.w)};
        int e0 = f4 * 4;
        *(ushort4*)(xh + e0) = u0;
        *(ushort4*)(xh + e0 + 4) = u1;
        if (b == 0 && t == 0) row_ptr[NNODES] = NEDGES;
    } else if (b < 3317) {                          // pooled: 512*384 floats
        ((float4*)pooled)[(b - 3125) * 256 + t] = make_float4(0.f, 0.f, 0.f, 0.f);
    } else if (b < 3513) {                          // counts: 50000 ints
        int i = (b - 3317) * 256 + t;
        if (i < NNODES) counts[i] = 0;
    } else {                                        // wsplit: 96 blocks
        int wb = b - 3513;
        const float* Ws[6] = {W0, W1, W2, W3, W4, W5};
        const float* W = Ws[wb >> 4];
        ushort* h = hi + (size_t)(wb >> 4) * 16384;
        ushort* l = lo + (size_t)(wb >> 4) * 16384;
        int chunk = wb & 15;
#pragma unroll
        for (int i = 0; i < 4; i++) {
            int idx = chunk * 1024 + i * 256 + t;
            int n = idx >> 7, k = idx & 127;
            ushort hh, ll;
            bf_split(W[k * 128 + n], hh, ll);
            h[n * 128 + k] = hh;
            l[n * 128 + k] = ll;
        }
    }
}

// ---------------------------------------------------------------- CSR build
__global__ __launch_bounds__(256) void hist_kernel(const int* __restrict__ dst,
                                                   int* __restrict__ counts, int E) {
    int i = blockIdx.x * 256 + threadIdx.x;
    if (i < E) atomicAdd(&counts[dst[i]], 1);
}

__global__ __launch_bounds__(256) void scan1_kernel(const int* __restrict__ counts,
                                                    int* __restrict__ partials, int n) {
    __shared__ int s[256];
    int i = blockIdx.x * 256 + threadIdx.x;
    int v = (i < n) ? counts[i] : 0;
    s[threadIdx.x] = v;
    __syncthreads();
    for (int off = 128; off > 0; off >>= 1) {
        if (threadIdx.x < off) s[threadIdx.x] += s[threadIdx.x + off];
        __syncthreads();
    }
    if (threadIdx.x == 0) partials[blockIdx.x] = s[0];
}

// scan3 with inline base reduction (no scan2 dispatch), nb<=256
__global__ __launch_bounds__(256) void scan3_kernel(const int* __restrict__ counts,
                                                    const int* __restrict__ partials,
                                                    int* __restrict__ row_ptr,
                                                    int* __restrict__ cursor, int n, int nb) {
    __shared__ int s[256];
    __shared__ int base_sh;
    int t = threadIdx.x;
    int pv = (t < (int)blockIdx.x && t < nb) ? partials[t] : 0;
    s[t] = pv;
    __syncthreads();
    for (int off = 128; off > 0; off >>= 1) {
        if (t < off) s[t] += s[t + off];
        __syncthreads();
    }
    if (t == 0) base_sh = s[0];
    __syncthreads();
    int base = base_sh;
    int i = blockIdx.x * 256 + t;
    int v = (i < n) ? counts[i] : 0;
    __syncthreads();
    s[t] = v;
    __syncthreads();
    for (int off = 1; off < 256; off <<= 1) {
        int nv = (t >= off) ? s[t - off] : 0;
        __syncthreads();
        s[t] += nv;
        __syncthreads();
    }
    if (i < n) {
        int ex = base + s[t] - v;   // exclusive
        row_ptr[i] = ex;
        cursor[i] = ex;
    }
}

__global__ __launch_bounds__(256) void scatter_kernel(const int* __restrict__ src,
                                                      const int* __restrict__ dst,
                                                      int* __restrict__ cursor,
                                                      int* __restrict__ esrc, int E) {
    int i = blockIdx.x * 256 + threadIdx.x;
    if (i < E) {
        int p = atomicAdd(&cursor[dst[i]], 1);
        esrc[p] = src[i];
    }
}

// ------------------------------------------------------------- aggregation
// (R10/R11-proven) 2 nodes/wave, 32 lanes x 4 ch. Neighbors from bf16
// hi-plane (256B rows); self exact (fp32 x or hi+lo). fp32 accumulate ->
// exact-sum hi/lo split out.
template <bool SELF_F32>
__global__ __launch_bounds__(256) void agg_kernel(
    const float* __restrict__ xf,
    const ushort* __restrict__ phi, const ushort* __restrict__ plo,
    const int* __restrict__ rp, const int* __restrict__ esrc,
    ushort* __restrict__ ohi, ushort* __restrict__ olo, int n) {
    int wid  = (blockIdx.x * 256 + threadIdx.x) >> 6;
    int lane = threadIdx.x & 63;
    int node = wid * 2 + (lane >> 5);
    int q = lane & 31;
    if (node >= n) return;
    const ushort4* xh = (const ushort4*)phi;
    float4 acc;
    if (SELF_F32) {
        acc = ((const float4*)xf)[(size_t)node * 32 + q];
    } else {
        ushort4 sh = xh[(size_t)node * 32 + q];
        ushort4 sl = ((const ushort4*)plo)[(size_t)node * 32 + q];
        acc.x = b2f(sh.x) + b2f(sl.x);
        acc.y = b2f(sh.y) + b2f(sl.y);
        acc.z = b2f(sh.z) + b2f(sl.z);
        acc.w = b2f(sh.w) + b2f(sl.w);
    }
    int beg = rp[node], end = rp[node + 1];
    int e = beg;
    for (; e + 8 <= end; e += 8) {
        int i0 = esrc[e],     i1 = esrc[e + 1], i2 = esrc[e + 2], i3 = esrc[e + 3];
        int i4 = esrc[e + 4], i5 = esrc[e + 5], i6 = esrc[e + 6], i7 = esrc[e + 7];
        ushort4 v0 = xh[(size_t)i0 * 32 + q];
        ushort4 v1 = xh[(size_t)i1 * 32 + q];
        ushort4 v2 = xh[(size_t)i2 * 32 + q];
        ushort4 v3 = xh[(size_t)i3 * 32 + q];
        ushort4 v4 = xh[(size_t)i4 * 32 + q];
        ushort4 v5 = xh[(size_t)i5 * 32 + q];
        ushort4 v6 = xh[(size_t)i6 * 32 + q];
        ushort4 v7 = xh[(size_t)i7 * 32 + q];
        acc.x += ((b2f(v0.x) + b2f(v1.x)) + (b2f(v2.x) + b2f(v3.x))) +
                 ((b2f(v4.x) + b2f(v5.x)) + (b2f(v6.x) + b2f(v7.x)));
        acc.y += ((b2f(v0.y) + b2f(v1.y)) + (b2f(v2.y) + b2f(v3.y))) +
                 ((b2f(v4.y) + b2f(v5.y)) + (b2f(v6.y) + b2f(v7.y)));
        acc.z += ((b2f(v0.z) + b2f(v1.z)) + (b2f(v2.z) + b2f(v3.z))) +
                 ((b2f(v4.z) + b2f(v5.z)) + (b2f(v6.z) + b2f(v7.z)));
        acc.w += ((b2f(v0.w) + b2f(v1.w)) + (b2f(v2.w) + b2f(v3.w))) +
                 ((b2f(v4.w) + b2f(v5.w)) + (b2f(v6.w) + b2f(v7.w)));
    }
    for (; e + 2 <= end; e += 2) {
        int i0 = esrc[e], i1 = esrc[e + 1];
        ushort4 v0 = xh[(size_t)i0 * 32 + q];
        ushort4 v1 = xh[(size_t)i1 * 32 + q];
        acc.x += b2f(v0.x) + b2f(v1.x); acc.y += b2f(v0.y) + b2f(v1.y);
        acc.z += b2f(v0.z) + b2f(v1.z); acc.w += b2f(v0.w) + b2f(v1.w);
    }
    for (; e < end; e++) {
        ushort4 v = xh[(size_t)esrc[e] * 32 + q];
        acc.x += b2f(v.x); acc.y += b2f(v.y); acc.z += b2f(v.z); acc.w += b2f(v.w);
    }
    ushort4 hh, ll;
    bf_split(acc.x, hh.x, ll.x);
    bf_split(acc.y, hh.y, ll.y);
    bf_split(acc.z, hh.z, ll.z);
    bf_split(acc.w, hh.w, ll.w);
    *(ushort4*)(ohi + (size_t)node * 128 + q * 4) = hh;
    *(ushort4*)(olo + (size_t)node * 128 + q * 4) = ll;
}

// --------------------------------------------------------------- fused MLP
// (R11-proven 128-row tile, <40us) C = act( BN_ReLU( A@W1 ) @ W2 ), split-
// bf16 MFMA, wave tile 64x64 = 4x4 (48 MFMA/kb hides W-frag latency — R12's
// 32x64 tile exposed it: 44.8us). Mean-pool fused in epilogue: outputs to
// LDS P[128][132] fp32 (unions dead A/H smem), run-length reduce over sorted
// batch, ~1.7 atomics/thread. L3 layer skips plane writes entirely.
#define HP 136
template <bool RELU_OUT, bool WRITE_PLANES>
__global__ __launch_bounds__(256) void mlp_kernel(
    const ushort* __restrict__ Ahi, const ushort* __restrict__ Alo,
    const ushort* __restrict__ W1hi, const ushort* __restrict__ W1lo,
    const ushort* __restrict__ W2hi, const ushort* __restrict__ W2lo,
    const float* __restrict__ b1, const float* __restrict__ gm,
    const float* __restrict__ bt, const float* __restrict__ rm,
    const float* __restrict__ rv, const float* __restrict__ b2,
    ushort* __restrict__ Chi, ushort* __restrict__ Clo,
    const int* __restrict__ batch, float* __restrict__ pooled, int poff, int M) {
    __shared__ __align__(16) ushort smem[2 * 128 * HP];   // 69632 B
    __shared__ int bsm[128];
#define AS(b_, p_, o_) smem[(((b_) * 2 + (p_)) << 12) + (o_)]
#define HS(p_, o_) smem[(p_)*128 * HP + (o_)]
    const int t = threadIdx.x;
    const int lane = t & 63;
    const int wv = t >> 6;
    const int wr = wv >> 1, wc = wv & 1;
    const int row0 = blockIdx.x * 128;
    const int g = lane >> 4, c = lane & 15;

    if (t < 128) bsm[t] = (row0 + t < M) ? batch[row0 + t] : -1;

    const int m0 = t >> 2,  k80 = (t & 3) * 8;
    const int m1 = m0 + 64;
    int r0 = row0 + m0; if (r0 >= M) r0 = M - 1;
    int r1 = row0 + m1; if (r1 >= M) r1 = M - 1;
    const size_t ga0 = (size_t)r0 * 128 + k80;
    const size_t ga1 = (size_t)r1 * 128 + k80;
    const int la0 = m0 * 32 + k80, la1 = m1 * 32 + k80;

    f32x4 acc[4][4];
#pragma unroll
    for (int i = 0; i < 4; i++)
#pragma unroll
        for (int j = 0; j < 4; j++) acc[i][j] = (f32x4){0.f, 0.f, 0.f, 0.f};

    uint4 ph0 = *(const uint4*)(Ahi + ga0);
    uint4 ph1 = *(const uint4*)(Ahi + ga1);
    uint4 pl0 = *(const uint4*)(Alo + ga0);
    uint4 pl1 = *(const uint4*)(Alo + ga1);
    *(uint4*)&AS(0, 0, la0) = ph0;
    *(uint4*)&AS(0, 0, la1) = ph1;
    *(uint4*)&AS(0, 1, la0) = pl0;
    *(uint4*)&AS(0, 1, la1) = pl1;
    __syncthreads();

    // ---------------- phase 1: A @ W1
    int cur = 0;
    for (int kb = 0; kb < 4; kb++) {
        bf16x8 bh[4], bl[4];
#pragma unroll
        for (int ct = 0; ct < 4; ct++) {
            const size_t wo = (size_t)(wc * 64 + ct * 16 + c) * 128 + kb * 32 + g * 8;
            bh[ct] = *(const bf16x8*)(W1hi + wo);
            bl[ct] = *(const bf16x8*)(W1lo + wo);
        }
        if (kb < 3) {
            const size_t o = (size_t)(kb + 1) * 32;
            ph0 = *(const uint4*)(Ahi + ga0 + o);
            ph1 = *(const uint4*)(Ahi + ga1 + o);
            pl0 = *(const uint4*)(Alo + ga0 + o);
            pl1 = *(const uint4*)(Alo + ga1 + o);
        }
        bf16x8 ah[4], al[4];
#pragma unroll
        for (int rt = 0; rt < 4; rt++) {
            int off = (wr * 64 + rt * 16 + c) * 32 + g * 8;
            ah[rt] = *(bf16x8*)&AS(cur, 0, off);
            al[rt] = *(bf16x8*)&AS(cur, 1, off);
        }
#pragma unroll
        for (int rt = 0; rt < 4; rt++)
#pragma unroll
            for (int ct = 0; ct < 4; ct++) {
                acc[rt][ct] = __builtin_amdgcn_mfma_f32_16x16x32_bf16(ah[rt], bh[ct], acc[rt][ct], 0, 0, 0);
                acc[rt][ct] = __builtin_amdgcn_mfma_f32_16x16x32_bf16(ah[rt], bl[ct], acc[rt][ct], 0, 0, 0);
                acc[rt][ct] = __builtin_amdgcn_mfma_f32_16x16x32_bf16(al[rt], bh[ct], acc[rt][ct], 0, 0, 0);
            }
        if (kb < 3) {
            *(uint4*)&AS(cur ^ 1, 0, la0) = ph0;
            *(uint4*)&AS(cur ^ 1, 0, la1) = ph1;
            *(uint4*)&AS(cur ^ 1, 1, la0) = pl0;
            *(uint4*)&AS(cur ^ 1, 1, la1) = pl1;
        }
        __syncthreads();   // final iter: all As reads done -> H may alias
        cur ^= 1;
    }

    // ---------------- BN + ReLU -> H (hi/lo bf16) in LDS
    {
        float cs[4], ca[4];
#pragma unroll
        for (int ct = 0; ct < 4; ct++) {
            int n = wc * 64 + ct * 16 + c;
            float s = gm[n] * rsqrtf(rv[n] + BN_EPS);
            cs[ct] = s;
            ca[ct] = (b1[n] - rm[n]) * s + bt[n];
        }
#pragma unroll
        for (int rt = 0; rt < 4; rt++)
#pragma unroll
            for (int r = 0; r < 4; r++) {
                int row = wr * 64 + rt * 16 + g * 4 + r;
#pragma unroll
                for (int ct = 0; ct < 4; ct++) {
                    int col = wc * 64 + ct * 16 + c;
                    float v = fmaxf(acc[rt][ct][r] * cs[ct] + ca[ct], 0.f);
                    ushort hh, ll;
                    bf_split(v, hh, ll);
                    HS(0, row * HP + col) = hh;
                    HS(1, row * HP + col) = ll;
                }
            }
    }
    __syncthreads();

    // ---------------- phase 2: H @ W2
#pragma unroll
    for (int i = 0; i < 4; i++)
#pragma unroll
        for (int j = 0; j < 4; j++) acc[i][j] = (f32x4){0.f, 0.f, 0.f, 0.f};

    for (int kb = 0; kb < 4; kb++) {
        bf16x8 bh[4], bl[4];
#pragma unroll
        for (int ct = 0; ct < 4; ct++) {
            const size_t wo = (size_t)(wc * 64 + ct * 16 + c) * 128 + kb * 32 + g * 8;
            bh[ct] = *(const bf16x8*)(W2hi + wo);
            bl[ct] = *(const bf16x8*)(W2lo + wo);
        }
        bf16x8 ah[4], al[4];
#pragma unroll
        for (int rt = 0; rt < 4; rt++) {
            int off = (wr * 64 + rt * 16 + c) * HP + kb * 32 + g * 8;
            ah[rt] = *(bf16x8*)&HS(0, off);
            al[rt] = *(bf16x8*)&HS(1, off);
        }
#pragma unroll
        for (int rt = 0; rt < 4; rt++)
#pragma unroll
            for (int ct = 0; ct < 4; ct++) {
                acc[rt][ct] = __builtin_amdgcn_mfma_f32_16x16x32_bf16(ah[rt], bh[ct], acc[rt][ct], 0, 0, 0);
                acc[rt][ct] = __builtin_amdgcn_mfma_f32_16x16x32_bf16(ah[rt], bl[ct], acc[rt][ct], 0, 0, 0);
                acc[rt][ct] = __builtin_amdgcn_mfma_f32_16x16x32_bf16(al[rt], bh[ct], acc[rt][ct], 0, 0, 0);
            }
    }
    __syncthreads();   // all H reads done -> P may overwrite smem

    // ---------------- epilogue: +b2 (,ReLU) -> planes + LDS P for pooling
    float* P = (float*)smem;   // [128][132] fp32 = 67584B (in 69632B smem)
    {
        float ca2[4];
#pragma unroll
        for (int ct = 0; ct < 4; ct++) ca2[ct] = b2[wc * 64 + ct * 16 + c];
#pragma unroll
        for (int rt = 0; rt < 4; rt++)
#pragma unroll
            for (int r = 0; r < 4; r++) {
                int rl = wr * 64 + rt * 16 + g * 4 + r;
                int row = row0 + rl;
                bool valid = row < M;
#pragma unroll
                for (int ct = 0; ct < 4; ct++) {
                    int col = wc * 64 + ct * 16 + c;
                    float v = acc[rt][ct][r] + ca2[ct];
                    if (RELU_OUT) v = fmaxf(v, 0.f);
                    P[rl * 132 + col] = valid ? v : 0.f;
                    if (WRITE_PLANES && valid) {
                        ushort hh, ll;
                        bf_split(v, hh, ll);
                        Chi[(size_t)row * 128 + col] = hh;
                        Clo[(size_t)row * 128 + col] = ll;
                    }
                }
            }
    }
    __syncthreads();

    // ---------------- fused mean-pool contribution (batch is sorted)
    {
        int col = t & 127;
        int rbase = (t >> 7) * 64;   // rows 0..63 or 64..127
        int gcur = bsm[rbase];
        float accp = 0.f;
#pragma unroll 8
        for (int r = 0; r < 64; r++) {
            int gg = bsm[rbase + r];
            if (gg != gcur) {        // wave-uniform branch (sorted batch)
                if (gcur >= 0) atomicAdd(&pooled[gcur * 384 + poff + col], accp);
                accp = 0.f;
                gcur = gg;
            }
            accp += P[(rbase + r) * 132 + col];
        }
        if (gcur >= 0) atomicAdd(&pooled[gcur * 384 + poff + col], accp);
    }
#undef AS
#undef HS
}

// ------------------------------------------------------------------- final
__global__ __launch_bounds__(128) void final_kernel(const float* __restrict__ pooled,
                                                    const int* __restrict__ batch,
                                                    const float* __restrict__ W,
                                                    const float* __restrict__ b,
                                                    float* __restrict__ out, int n) {
    __shared__ float ps[384];
    int gph = blockIdx.x, t = threadIdx.x;
    int lo1 = 0, hi1 = n;
    while (lo1 < hi1) { int mid = (lo1 + hi1) >> 1; if (batch[mid] < gph) lo1 = mid + 1; else hi1 = mid; }
    int start = lo1;
    int lo2 = start, hi2 = n;
    while (lo2 < hi2) { int mid = (lo2 + hi2) >> 1; if (batch[mid] < gph + 1) lo2 = mid + 1; else hi2 = mid; }
    int cnt = lo2 - start;
    float inv = 1.f / (float)(cnt > 0 ? cnt : 1);
    for (int i = t; i < 384; i += 128) ps[i] = pooled[gph * 384 + i] * inv;
    __syncthreads();
    float acc = b[t];
#pragma unroll 8
    for (int k = 0; k < 384; k++) acc += ps[k] * W[k * 128 + t];
    out[gph * 128 + t] = acc;
}

// ------------------------------------------------------------------ launch
extern "C" void kernel_launch(void* const* d_in, const int* in_sizes, int n_in,
                              void* d_out, int out_size, void* d_ws, size_t ws_size,
                              hipStream_t stream) {
    const float* x     = (const float*)d_in[0];
    const int*   edge  = (const int*)d_in[1];
    const int*   batch = (const int*)d_in[2];
    const float* p[32];
    for (int i = 0; i < n_in && i < 32; i++) p[i] = (const float*)d_in[i];
    const float* lin_W = p[27];
    const float* lin_b = p[28];

    char* w = (char*)d_ws;
    auto alloc = [&](size_t bytes) { void* r = (void*)w; w += (bytes + 255) & ~(size_t)255; return r; };
    const size_t PL = (size_t)NNODES * 128;
    ushort* thi   = (ushort*)alloc(PL * 2);   // agg out planes
    ushort* tlo   = (ushort*)alloc(PL * 2);
    ushort* xh0   = (ushort*)alloc(PL * 2);   // bf16(x); dead after agg L1
    ushort* p1h   = (ushort*)alloc(PL * 2);
    ushort* p1l   = (ushort*)alloc(PL * 2);
    ushort* p2h   = xh0;                      // alias: xh0 dead before mlp L2 writes
    ushort* p2l   = (ushort*)alloc(PL * 2);
    float* pooled = (float*)alloc((size_t)NGRAPHS * 384 * 4);
    int* counts   = (int*)alloc((size_t)NNODES * 4);
    int* cursor   = (int*)alloc((size_t)NNODES * 4);
    int* row_ptr  = (int*)alloc((size_t)(NNODES + 1) * 4);
    int* esrc     = (int*)alloc((size_t)NEDGES * 4);
    int* partials = (int*)alloc(256 * 4);
    ushort* wt_hi = (ushort*)alloc((size_t)6 * 16384 * 2);
    ushort* wt_lo = (ushort*)alloc((size_t)6 * 16384 * 2);

    const int* src = edge;
    const int* dst = edge + NEDGES;

    // --- prep: x->bf16, zero pooled/counts, row_ptr[N], wsplit (1 dispatch)
    prep_kernel<<<3609, 256, 0, stream>>>(x, xh0, pooled, counts, row_ptr,
                                          p[3], p[9], p[11], p[17], p[19], p[25],
                                          wt_hi, wt_lo);

    // --- CSR build: 4 dispatches
    int nb = (NNODES + 255) / 256;  // 196
    hist_kernel<<<(NEDGES + 255) / 256, 256, 0, stream>>>(dst, counts, NEDGES);
    scan1_kernel<<<nb, 256, 0, stream>>>(counts, partials, NNODES);
    scan3_kernel<<<nb, 256, 0, stream>>>(counts, partials, row_ptr, cursor, NNODES, nb);
    scatter_kernel<<<(NEDGES + 255) / 256, 256, 0, stream>>>(src, dst, cursor, esrc, NEDGES);

    // --- 3 GIN layers (mlp fuses the mean-pool contribution)
    int mlp_grid = (NNODES + 127) / 128;            // 391
    int agg_grid = (NNODES / 2 * 64 + 255) / 256;   // 6250

    // layer 1: self fp32 x, neighbors xh0
    agg_kernel<true><<<agg_grid, 256, 0, stream>>>(x, xh0, nullptr, row_ptr, esrc,
                                                   thi, tlo, NNODES);
    mlp_kernel<true, true><<<mlp_grid, 256, 0, stream>>>(thi, tlo,
        wt_hi + 0 * 16384, wt_lo + 0 * 16384, wt_hi + 1 * 16384, wt_lo + 1 * 16384,
        p[4], p[5], p[6], p[7], p[8], p[10], p1h, p1l, batch, pooled, 0, NNODES);
    // layer 2
    agg_kernel<false><<<agg_grid, 256, 0, stream>>>(nullptr, p1h, p1l, row_ptr, esrc,
                                                    thi, tlo, NNODES);
    mlp_kernel<true, true><<<mlp_grid, 256, 0, stream>>>(thi, tlo,
        wt_hi + 2 * 16384, wt_lo + 2 * 16384, wt_hi + 3 * 16384, wt_lo + 3 * 16384,
        p[12], p[13], p[14], p[15], p[16], p[18], p2h, p2l, batch, pooled, 128, NNODES);
    // layer 3 (no relu, no plane writes — pool-only output)
    agg_kernel<false><<<agg_grid, 256, 0, stream>>>(nullptr, p2h, p2l, row_ptr, esrc,
                                                    thi, tlo, NNODES);
    mlp_kernel<false, false><<<mlp_grid, 256, 0, stream>>>(thi, tlo,
        wt_hi + 4 * 16384, wt_lo + 4 * 16384, wt_hi + 5 * 16384, wt_lo + 5 * 16384,
        p[20], p[21], p[22], p[23], p[24], p[26], nullptr, nullptr, batch, pooled, 256, NNODES);

    // --- final linear on mean-pooled JK-concat
    final_kernel<<<NGRAPHS, 128, 0, stream>>>(pooled, batch, lin_W, lin_b,
                                              (float*)d_out, NNODES);
}

// Round 14
// 365.876 us; speedup vs baseline: 1.1296x; 1.0414x over previous
//
#include <hip/hip_runtime.h>
#include <hip/hip_bf16.h>

#define NNODES 50000
#define NEDGES 600000
#define NGRAPHS 512
#define BN_EPS 1e-5f

typedef short bf16x8 __attribute__((ext_vector_type(8)));
typedef float f32x4 __attribute__((ext_vector_type(4)));

// split fp32 -> hi/lo bf16 (RNE); hi+lo carries ~16 mantissa bits (weights only)
__device__ __forceinline__ void bf_split(float x, ushort& h, ushort& l) {
    __hip_bfloat16 bh = __float2bfloat16(x);
    float r = x - __bfloat162float(bh);
    __hip_bfloat16 bl = __float2bfloat16(r);
    h = __builtin_bit_cast(ushort, bh);
    l = __builtin_bit_cast(ushort, bl);
}
__device__ __forceinline__ ushort f2b(float x) {
    return __builtin_bit_cast(ushort, __float2bfloat16(x));
}
__device__ __forceinline__ float b2f(ushort u) {
    union { uint i; float f; } c; c.i = ((uint)u) << 16; return c.f;
}

// ------------------------------------------------------------------- prep
// One dispatch: x->bf16 (blocks 0..3124), zero pooled (3125..3316), zero
// counts (3317..3512), wsplit 6 matrices (3513..3608), row_ptr[N] init.
__global__ __launch_bounds__(256) void prep_kernel(
    const float* __restrict__ x, ushort* __restrict__ xh,
    float* __restrict__ pooled, int* __restrict__ counts, int* __restrict__ row_ptr,
    const float* W0, const float* W1, const float* W2, const float* W3,
    const float* W4, const float* W5, ushort* __restrict__ hi, ushort* __restrict__ lo) {
    int b = blockIdx.x, t = threadIdx.x;
    if (b < 3125) {                                 // x: 6.4M floats -> bf16
        int f4 = b * 512 + t * 2;
        float4 a0 = ((const float4*)x)[f4];
        float4 a1 = ((const float4*)x)[f4 + 1];
        ushort4 u0 = {f2b(a0.x), f2b(a0.y), f2b(a0.z), f2b(a0.w)};
        ushort4 u1 = {f2b(a1.x), f2b(a1.y), f2b(a1.z), f2b(a1.w)};
        int e0 = f4 * 4;
        *(ushort4*)(xh + e0) = u0;
        *(ushort4*)(xh + e0 + 4) = u1;
        if (b == 0 && t == 0) row_ptr[NNODES] = NEDGES;
    } else if (b < 3317) {                          // pooled: 512*384 floats
        ((float4*)pooled)[(b - 3125) * 256 + t] = make_float4(0.f, 0.f, 0.f, 0.f);
    } else if (b < 3513) {                          // counts: 50000 ints
        int i = (b - 3317) * 256 + t;
        if (i < NNODES) counts[i] = 0;
    } else {                                        // wsplit: 96 blocks
        int wb = b - 3513;
        const float* Ws[6] = {W0, W1, W2, W3, W4, W5};
        const float* W = Ws[wb >> 4];
        ushort* h = hi + (size_t)(wb >> 4) * 16384;
        ushort* l = lo + (size_t)(wb >> 4) * 16384;
        int chunk = wb & 15;
#pragma unroll
        for (int i = 0; i < 4; i++) {
            int idx = chunk * 1024 + i * 256 + t;
            int n = idx >> 7, k = idx & 127;
            ushort hh, ll;
            bf_split(W[k * 128 + n], hh, ll);
            h[n * 128 + k] = hh;
            l[n * 128 + k] = ll;
        }
    }
}

// ---------------------------------------------------------------- CSR build
__global__ __launch_bounds__(256) void hist_kernel(const int* __restrict__ dst,
                                                   int* __restrict__ counts, int E) {
    int i = blockIdx.x * 256 + threadIdx.x;
    if (i < E) atomicAdd(&counts[dst[i]], 1);
}

__global__ __launch_bounds__(256) void scan1_kernel(const int* __restrict__ counts,
                                                    int* __restrict__ partials, int n) {
    __shared__ int s[256];
    int i = blockIdx.x * 256 + threadIdx.x;
    int v = (i < n) ? counts[i] : 0;
    s[threadIdx.x] = v;
    __syncthreads();
    for (int off = 128; off > 0; off >>= 1) {
        if (threadIdx.x < off) s[threadIdx.x] += s[threadIdx.x + off];
        __syncthreads();
    }
    if (threadIdx.x == 0) partials[blockIdx.x] = s[0];
}

// scan3 with inline base reduction (no scan2 dispatch), nb<=256
__global__ __launch_bounds__(256) void scan3_kernel(const int* __restrict__ counts,
                                                    const int* __restrict__ partials,
                                                    int* __restrict__ row_ptr,
                                                    int* __restrict__ cursor, int n, int nb) {
    __shared__ int s[256];
    __shared__ int base_sh;
    int t = threadIdx.x;
    int pv = (t < (int)blockIdx.x && t < nb) ? partials[t] : 0;
    s[t] = pv;
    __syncthreads();
    for (int off = 128; off > 0; off >>= 1) {
        if (t < off) s[t] += s[t + off];
        __syncthreads();
    }
    if (t == 0) base_sh = s[0];
    __syncthreads();
    int base = base_sh;
    int i = blockIdx.x * 256 + t;
    int v = (i < n) ? counts[i] : 0;
    __syncthreads();
    s[t] = v;
    __syncthreads();
    for (int off = 1; off < 256; off <<= 1) {
        int nv = (t >= off) ? s[t - off] : 0;
        __syncthreads();
        s[t] += nv;
        __syncthreads();
    }
    if (i < n) {
        int ex = base + s[t] - v;   // exclusive
        row_ptr[i] = ex;
        cursor[i] = ex;
    }
}

__global__ __launch_bounds__(256) void scatter_kernel(const int* __restrict__ src,
                                                      const int* __restrict__ dst,
                                                      int* __restrict__ cursor,
                                                      int* __restrict__ esrc, int E) {
    int i = blockIdx.x * 256 + threadIdx.x;
    if (i < E) {
        int p = atomicAdd(&cursor[dst[i]], 1);
        esrc[p] = src[i];
    }
}

// ------------------------------------------------------------- aggregation
// 2 nodes/wave, 32 lanes x 4 ch, neighbors from the single bf16 plane
// (256B rows). Self term: fp32 x for layer 1, plane for layers 2/3 (error
// ~2^-9 — same class as the R10-validated neighbor rounding). Output is ONE
// bf16 plane (halves R13's write traffic).
template <bool SELF_F32>
__global__ __launch_bounds__(256) void agg_kernel(
    const float* __restrict__ xf, const ushort* __restrict__ phi,
    const int* __restrict__ rp, const int* __restrict__ esrc,
    ushort* __restrict__ ohi, int n) {
    int wid  = (blockIdx.x * 256 + threadIdx.x) >> 6;
    int lane = threadIdx.x & 63;
    int node = wid * 2 + (lane >> 5);
    int q = lane & 31;
    if (node >= n) return;
    const ushort4* xh = (const ushort4*)phi;
    float4 acc;
    if (SELF_F32) {
        acc = ((const float4*)xf)[(size_t)node * 32 + q];
    } else {
        ushort4 sh = xh[(size_t)node * 32 + q];
        acc.x = b2f(sh.x); acc.y = b2f(sh.y); acc.z = b2f(sh.z); acc.w = b2f(sh.w);
    }
    int beg = rp[node], end = rp[node + 1];
    int e = beg;
    for (; e + 8 <= end; e += 8) {
        int i0 = esrc[e],     i1 = esrc[e + 1], i2 = esrc[e + 2], i3 = esrc[e + 3];
        int i4 = esrc[e + 4], i5 = esrc[e + 5], i6 = esrc[e + 6], i7 = esrc[e + 7];
        ushort4 v0 = xh[(size_t)i0 * 32 + q];
        ushort4 v1 = xh[(size_t)i1 * 32 + q];
        ushort4 v2 = xh[(size_t)i2 * 32 + q];
        ushort4 v3 = xh[(size_t)i3 * 32 + q];
        ushort4 v4 = xh[(size_t)i4 * 32 + q];
        ushort4 v5 = xh[(size_t)i5 * 32 + q];
        ushort4 v6 = xh[(size_t)i6 * 32 + q];
        ushort4 v7 = xh[(size_t)i7 * 32 + q];
        acc.x += ((b2f(v0.x) + b2f(v1.x)) + (b2f(v2.x) + b2f(v3.x))) +
                 ((b2f(v4.x) + b2f(v5.x)) + (b2f(v6.x) + b2f(v7.x)));
        acc.y += ((b2f(v0.y) + b2f(v1.y)) + (b2f(v2.y) + b2f(v3.y))) +
                 ((b2f(v4.y) + b2f(v5.y)) + (b2f(v6.y) + b2f(v7.y)));
        acc.z += ((b2f(v0.z) + b2f(v1.z)) + (b2f(v2.z) + b2f(v3.z))) +
                 ((b2f(v4.z) + b2f(v5.z)) + (b2f(v6.z) + b2f(v7.z)));
        acc.w += ((b2f(v0.w) + b2f(v1.w)) + (b2f(v2.w) + b2f(v3.w))) +
                 ((b2f(v4.w) + b2f(v5.w)) + (b2f(v6.w) + b2f(v7.w)));
    }
    for (; e + 2 <= end; e += 2) {
        int i0 = esrc[e], i1 = esrc[e + 1];
        ushort4 v0 = xh[(size_t)i0 * 32 + q];
        ushort4 v1 = xh[(size_t)i1 * 32 + q];
        acc.x += b2f(v0.x) + b2f(v1.x); acc.y += b2f(v0.y) + b2f(v1.y);
        acc.z += b2f(v0.z) + b2f(v1.z); acc.w += b2f(v0.w) + b2f(v1.w);
    }
    for (; e < end; e++) {
        ushort4 v = xh[(size_t)esrc[e] * 32 + q];
        acc.x += b2f(v.x); acc.y += b2f(v.y); acc.z += b2f(v.z); acc.w += b2f(v.w);
    }
    ushort4 hh = {f2b(acc.x), f2b(acc.y), f2b(acc.z), f2b(acc.w)};
    *(ushort4*)(ohi + (size_t)node * 128 + q * 4) = hh;
}

// --------------------------------------------------------------- fused MLP
// C = act( BN_ReLU( A@W1 ) @ W2 ), 128-row tile, wave tile 64x64 = 4x4.
// bf16 single-plane activations; W kept hi/lo -> 2 MFMA terms (A@Whi+A@Wlo).
// LDS 34.8KB (was 69.6) -> 4 blocks/CU. Sequence: A dbuf (16KB, in smem[0..8192))
// -> phase1 -> H bf16 (full smem) -> phase2 -> P bf16 (reuses H space) ->
// fused mean-pool (run-length over sorted batch, ~1.7 atomics/thread).
template <bool RELU_OUT, bool WRITE_PLANES>
__global__ __launch_bounds__(256) void mlp_kernel(
    const ushort* __restrict__ Ah,
    const ushort* __restrict__ W1hi, const ushort* __restrict__ W1lo,
    const ushort* __restrict__ W2hi, const ushort* __restrict__ W2lo,
    const float* __restrict__ b1, const float* __restrict__ gm,
    const float* __restrict__ bt, const float* __restrict__ rm,
    const float* __restrict__ rv, const float* __restrict__ b2,
    ushort* __restrict__ Ch,
    const int* __restrict__ batch, float* __restrict__ pooled, int poff, int M) {
    __shared__ __align__(16) ushort smem[128 * 136];   // 34816 B
    __shared__ int bsm[128];
    // A dbuf: smem[buf*4096 + m*32 + k], buf in {0,1}
    // H / P:  smem[row*136 + col]
    const int t = threadIdx.x;
    const int lane = t & 63;
    const int wv = t >> 6;
    const int wr = wv >> 1, wc = wv & 1;
    const int row0 = blockIdx.x * 128;
    const int g = lane >> 4, c = lane & 15;

    if (t < 128) bsm[t] = (row0 + t < M) ? batch[row0 + t] : -1;

    const int m0 = t >> 2,  k80 = (t & 3) * 8;
    const int m1 = m0 + 64;
    int r0 = row0 + m0; if (r0 >= M) r0 = M - 1;
    int r1 = row0 + m1; if (r1 >= M) r1 = M - 1;
    const size_t ga0 = (size_t)r0 * 128 + k80;
    const size_t ga1 = (size_t)r1 * 128 + k80;
    const int la0 = m0 * 32 + k80, la1 = m1 * 32 + k80;

    f32x4 acc[4][4];
#pragma unroll
    for (int i = 0; i < 4; i++)
#pragma unroll
        for (int j = 0; j < 4; j++) acc[i][j] = (f32x4){0.f, 0.f, 0.f, 0.f};

    uint4 ph0 = *(const uint4*)(Ah + ga0);
    uint4 ph1 = *(const uint4*)(Ah + ga1);
    *(uint4*)&smem[la0] = ph0;
    *(uint4*)&smem[la1] = ph1;
    __syncthreads();

    // ---------------- phase 1: A @ W1 (2 terms: A@W1hi + A@W1lo)
    int cur = 0;
    for (int kb = 0; kb < 4; kb++) {
        bf16x8 bh[4], bl[4];
#pragma unroll
        for (int ct = 0; ct < 4; ct++) {
            const size_t wo = (size_t)(wc * 64 + ct * 16 + c) * 128 + kb * 32 + g * 8;
            bh[ct] = *(const bf16x8*)(W1hi + wo);
            bl[ct] = *(const bf16x8*)(W1lo + wo);
        }
        if (kb < 3) {
            const size_t o = (size_t)(kb + 1) * 32;
            ph0 = *(const uint4*)(Ah + ga0 + o);
            ph1 = *(const uint4*)(Ah + ga1 + o);
        }
        bf16x8 ah[4];
#pragma unroll
        for (int rt = 0; rt < 4; rt++) {
            int off = cur * 4096 + (wr * 64 + rt * 16 + c) * 32 + g * 8;
            ah[rt] = *(bf16x8*)&smem[off];
        }
#pragma unroll
        for (int rt = 0; rt < 4; rt++)
#pragma unroll
            for (int ct = 0; ct < 4; ct++) {
                acc[rt][ct] = __builtin_amdgcn_mfma_f32_16x16x32_bf16(ah[rt], bh[ct], acc[rt][ct], 0, 0, 0);
                acc[rt][ct] = __builtin_amdgcn_mfma_f32_16x16x32_bf16(ah[rt], bl[ct], acc[rt][ct], 0, 0, 0);
            }
        if (kb < 3) {
            *(uint4*)&smem[(cur ^ 1) * 4096 + la0] = ph0;
            *(uint4*)&smem[(cur ^ 1) * 4096 + la1] = ph1;
        }
        __syncthreads();   // final iter: all A reads done -> H may overwrite
        cur ^= 1;
    }

    // ---------------- BN + ReLU -> H (bf16, full smem)
    {
        float cs[4], ca[4];
#pragma unroll
        for (int ct = 0; ct < 4; ct++) {
            int n = wc * 64 + ct * 16 + c;
            float s = gm[n] * rsqrtf(rv[n] + BN_EPS);
            cs[ct] = s;
            ca[ct] = (b1[n] - rm[n]) * s + bt[n];
        }
#pragma unroll
        for (int rt = 0; rt < 4; rt++)
#pragma unroll
            for (int r = 0; r < 4; r++) {
                int row = wr * 64 + rt * 16 + g * 4 + r;
#pragma unroll
                for (int ct = 0; ct < 4; ct++) {
                    int col = wc * 64 + ct * 16 + c;
                    float v = fmaxf(acc[rt][ct][r] * cs[ct] + ca[ct], 0.f);
                    smem[row * 136 + col] = f2b(v);
                }
            }
    }
    __syncthreads();

    // ---------------- phase 2: H @ W2 (2 terms)
#pragma unroll
    for (int i = 0; i < 4; i++)
#pragma unroll
        for (int j = 0; j < 4; j++) acc[i][j] = (f32x4){0.f, 0.f, 0.f, 0.f};

    for (int kb = 0; kb < 4; kb++) {
        bf16x8 bh[4], bl[4];
#pragma unroll
        for (int ct = 0; ct < 4; ct++) {
            const size_t wo = (size_t)(wc * 64 + ct * 16 + c) * 128 + kb * 32 + g * 8;
            bh[ct] = *(const bf16x8*)(W2hi + wo);
            bl[ct] = *(const bf16x8*)(W2lo + wo);
        }
        bf16x8 ah[4];
#pragma unroll
        for (int rt = 0; rt < 4; rt++) {
            int off = (wr * 64 + rt * 16 + c) * 136 + kb * 32 + g * 8;
            ah[rt] = *(bf16x8*)&smem[off];
        }
#pragma unroll
        for (int rt = 0; rt < 4; rt++)
#pragma unroll
            for (int ct = 0; ct < 4; ct++) {
                acc[rt][ct] = __builtin_amdgcn_mfma_f32_16x16x32_bf16(ah[rt], bh[ct], acc[rt][ct], 0, 0, 0);
                acc[rt][ct] = __builtin_amdgcn_mfma_f32_16x16x32_bf16(ah[rt], bl[ct], acc[rt][ct], 0, 0, 0);
            }
    }
    __syncthreads();   // all H reads done -> P may overwrite smem

    // ---------------- epilogue: +b2 (,ReLU) -> bf16 plane + LDS P (bf16)
    {
        float ca2[4];
#pragma unroll
        for (int ct = 0; ct < 4; ct++) ca2[ct] = b2[wc * 64 + ct * 16 + c];
#pragma unroll
        for (int rt = 0; rt < 4; rt++)
#pragma unroll
            for (int r = 0; r < 4; r++) {
                int rl = wr * 64 + rt * 16 + g * 4 + r;
                int row = row0 + rl;
                bool valid = row < M;
#pragma unroll
                for (int ct = 0; ct < 4; ct++) {
                    int col = wc * 64 + ct * 16 + c;
                    float v = acc[rt][ct][r] + ca2[ct];
                    if (RELU_OUT) v = fmaxf(v, 0.f);
                    ushort hh = f2b(valid ? v : 0.f);
                    smem[rl * 136 + col] = hh;
                    if (WRITE_PLANES && valid) Ch[(size_t)row * 128 + col] = hh;
                }
            }
    }
    __syncthreads();

    // ---------------- fused mean-pool contribution (batch is sorted)
    {
        int col = t & 127;
        int rbase = (t >> 7) * 64;   // rows 0..63 or 64..127
        int gcur = bsm[rbase];
        float accp = 0.f;
#pragma unroll 8
        for (int r = 0; r < 64; r++) {
            int gg = bsm[rbase + r];
            if (gg != gcur) {        // wave-uniform branch (sorted batch)
                if (gcur >= 0) atomicAdd(&pooled[gcur * 384 + poff + col], accp);
                accp = 0.f;
                gcur = gg;
            }
            accp += b2f(smem[(rbase + r) * 136 + col]);
        }
        if (gcur >= 0) atomicAdd(&pooled[gcur * 384 + poff + col], accp);
    }
}

// ------------------------------------------------------------------- final
__global__ __launch_bounds__(128) void final_kernel(const float* __restrict__ pooled,
                                                    const int* __restrict__ batch,
                                                    const float* __restrict__ W,
                                                    const float* __restrict__ b,
                                                    float* __restrict__ out, int n) {
    __shared__ float ps[384];
    int gph = blockIdx.x, t = threadIdx.x;
    int lo1 = 0, hi1 = n;
    while (lo1 < hi1) { int mid = (lo1 + hi1) >> 1; if (batch[mid] < gph) lo1 = mid + 1; else hi1 = mid; }
    int start = lo1;
    int lo2 = start, hi2 = n;
    while (lo2 < hi2) { int mid = (lo2 + hi2) >> 1; if (batch[mid] < gph + 1) lo2 = mid + 1; else hi2 = mid; }
    int cnt = lo2 - start;
    float inv = 1.f / (float)(cnt > 0 ? cnt : 1);
    for (int i = t; i < 384; i += 128) ps[i] = pooled[gph * 384 + i] * inv;
    __syncthreads();
    float acc = b[t];
#pragma unroll 8
    for (int k = 0; k < 384; k++) acc += ps[k] * W[k * 128 + t];
    out[gph * 128 + t] = acc;
}

// ------------------------------------------------------------------ launch
extern "C" void kernel_launch(void* const* d_in, const int* in_sizes, int n_in,
                              void* d_out, int out_size, void* d_ws, size_t ws_size,
                              hipStream_t stream) {
    const float* x     = (const float*)d_in[0];
    const int*   edge  = (const int*)d_in[1];
    const int*   batch = (const int*)d_in[2];
    const float* p[32];
    for (int i = 0; i < n_in && i < 32; i++) p[i] = (const float*)d_in[i];
    const float* lin_W = p[27];
    const float* lin_b = p[28];

    char* w = (char*)d_ws;
    auto alloc = [&](size_t bytes) { void* r = (void*)w; w += (bytes + 255) & ~(size_t)255; return r; };
    const size_t PL = (size_t)NNODES * 128;
    ushort* thi   = (ushort*)alloc(PL * 2);   // agg out plane
    ushort* xh0   = (ushort*)alloc(PL * 2);   // bf16(x); dead after agg L1
    ushort* p1h   = (ushort*)alloc(PL * 2);
    ushort* p2h   = xh0;                      // alias: xh0 dead before mlp L2 writes
    float* pooled = (float*)alloc((size_t)NGRAPHS * 384 * 4);
    int* counts   = (int*)alloc((size_t)NNODES * 4);
    int* cursor   = (int*)alloc((size_t)NNODES * 4);
    int* row_ptr  = (int*)alloc((size_t)(NNODES + 1) * 4);
    int* esrc     = (int*)alloc((size_t)NEDGES * 4);
    int* partials = (int*)alloc(256 * 4);
    ushort* wt_hi = (ushort*)alloc((size_t)6 * 16384 * 2);
    ushort* wt_lo = (ushort*)alloc((size_t)6 * 16384 * 2);

    const int* src = edge;
    const int* dst = edge + NEDGES;

    // --- prep: x->bf16, zero pooled/counts, row_ptr[N], wsplit (1 dispatch)
    prep_kernel<<<3609, 256, 0, stream>>>(x, xh0, pooled, counts, row_ptr,
                                          p[3], p[9], p[11], p[17], p[19], p[25],
                                          wt_hi, wt_lo);

    // --- CSR build: 4 dispatches
    int nb = (NNODES + 255) / 256;  // 196
    hist_kernel<<<(NEDGES + 255) / 256, 256, 0, stream>>>(dst, counts, NEDGES);
    scan1_kernel<<<nb, 256, 0, stream>>>(counts, partials, NNODES);
    scan3_kernel<<<nb, 256, 0, stream>>>(counts, partials, row_ptr, cursor, NNODES, nb);
    scatter_kernel<<<(NEDGES + 255) / 256, 256, 0, stream>>>(src, dst, cursor, esrc, NEDGES);

    // --- 3 GIN layers (mlp fuses the mean-pool contribution)
    int mlp_grid = (NNODES + 127) / 128;            // 391
    int agg_grid = (NNODES / 2 * 64 + 255) / 256;   // 6250

    // layer 1: self fp32 x, neighbors xh0
    agg_kernel<true><<<agg_grid, 256, 0, stream>>>(x, xh0, row_ptr, esrc, thi, NNODES);
    mlp_kernel<true, true><<<mlp_grid, 256, 0, stream>>>(thi,
        wt_hi + 0 * 16384, wt_lo + 0 * 16384, wt_hi + 1 * 16384, wt_lo + 1 * 16384,
        p[4], p[5], p[6], p[7], p[8], p[10], p1h, batch, pooled, 0, NNODES);
    // layer 2
    agg_kernel<false><<<agg_grid, 256, 0, stream>>>(nullptr, p1h, row_ptr, esrc, thi, NNODES);
    mlp_kernel<true, true><<<mlp_grid, 256, 0, stream>>>(thi,
        wt_hi + 2 * 16384, wt_lo + 2 * 16384, wt_hi + 3 * 16384, wt_lo + 3 * 16384,
        p[12], p[13], p[14], p[15], p[16], p[18], p2h, batch, pooled, 128, NNODES);
    // layer 3 (no relu, no plane writes — pool-only output)
    agg_kernel<false><<<agg_grid, 256, 0, stream>>>(nullptr, p2h, row_ptr, esrc, thi, NNODES);
    mlp_kernel<false, false><<<mlp_grid, 256, 0, stream>>>(thi,
        wt_hi + 4 * 16384, wt_lo + 4 * 16384, wt_hi + 5 * 16384, wt_lo + 5 * 16384,
        p[20], p[21], p[22], p[23], p[24], p[26], nullptr, batch, pooled, 256, NNODES);

    // --- final linear on mean-pooled JK-concat
    final_kernel<<<NGRAPHS, 128, 0, stream>>>(pooled, batch, lin_W, lin_b,
                                              (float*)d_out, NNODES);
}

// Round 15
// 363.820 us; speedup vs baseline: 1.1360x; 1.0057x over previous
//
#include <hip/hip_runtime.h>
#include <hip/hip_bf16.h>

#define NNODES 50000
#define NEDGES 600000
#define NGRAPHS 512
#define BN_EPS 1e-5f

typedef short bf16x8 __attribute__((ext_vector_type(8)));
typedef float f32x4 __attribute__((ext_vector_type(4)));

// split fp32 -> hi/lo bf16 (RNE); hi+lo carries ~16 mantissa bits (weights only)
__device__ __forceinline__ void bf_split(float x, ushort& h, ushort& l) {
    __hip_bfloat16 bh = __float2bfloat16(x);
    float r = x - __bfloat162float(bh);
    __hip_bfloat16 bl = __float2bfloat16(r);
    h = __builtin_bit_cast(ushort, bh);
    l = __builtin_bit_cast(ushort, bl);
}
__device__ __forceinline__ ushort f2b(float x) {
    return __builtin_bit_cast(ushort, __float2bfloat16(x));
}
__device__ __forceinline__ float b2f(ushort u) {
    union { uint i; float f; } c; c.i = ((uint)u) << 16; return c.f;
}

// ------------------------------------------------------------------- prep
// One dispatch: x->bf16 (blocks 0..3124), zero pooled (3125..3316), zero
// counts (3317..3512), wsplit 6 matrices (3513..3608), row_ptr[N] init.
__global__ __launch_bounds__(256) void prep_kernel(
    const float* __restrict__ x, ushort* __restrict__ xh,
    float* __restrict__ pooled, int* __restrict__ counts, int* __restrict__ row_ptr,
    const float* W0, const float* W1, const float* W2, const float* W3,
    const float* W4, const float* W5, ushort* __restrict__ hi, ushort* __restrict__ lo) {
    int b = blockIdx.x, t = threadIdx.x;
    if (b < 3125) {                                 // x: 6.4M floats -> bf16
        int f4 = b * 512 + t * 2;
        float4 a0 = ((const float4*)x)[f4];
        float4 a1 = ((const float4*)x)[f4 + 1];
        ushort4 u0 = {f2b(a0.x), f2b(a0.y), f2b(a0.z), f2b(a0.w)};
        ushort4 u1 = {f2b(a1.x), f2b(a1.y), f2b(a1.z), f2b(a1.w)};
        int e0 = f4 * 4;
        *(ushort4*)(xh + e0) = u0;
        *(ushort4*)(xh + e0 + 4) = u1;
        if (b == 0 && t == 0) row_ptr[NNODES] = NEDGES;
    } else if (b < 3317) {                          // pooled: 512*384 floats
        ((float4*)pooled)[(b - 3125) * 256 + t] = make_float4(0.f, 0.f, 0.f, 0.f);
    } else if (b < 3513) {                          // counts: 50000 ints
        int i = (b - 3317) * 256 + t;
        if (i < NNODES) counts[i] = 0;
    } else {                                        // wsplit: 96 blocks
        int wb = b - 3513;
        const float* Ws[6] = {W0, W1, W2, W3, W4, W5};
        const float* W = Ws[wb >> 4];
        ushort* h = hi + (size_t)(wb >> 4) * 16384;
        ushort* l = lo + (size_t)(wb >> 4) * 16384;
        int chunk = wb & 15;
#pragma unroll
        for (int i = 0; i < 4; i++) {
            int idx = chunk * 1024 + i * 256 + t;
            int n = idx >> 7, k = idx & 127;
            ushort hh, ll;
            bf_split(W[k * 128 + n], hh, ll);
            h[n * 128 + k] = hh;
            l[n * 128 + k] = ll;
        }
    }
}

// ---------------------------------------------------------------- CSR build
__global__ __launch_bounds__(256) void hist_kernel(const int* __restrict__ dst,
                                                   int* __restrict__ counts, int E) {
    int i = blockIdx.x * 256 + threadIdx.x;
    if (i < E) atomicAdd(&counts[dst[i]], 1);
}

__global__ __launch_bounds__(256) void scan1_kernel(const int* __restrict__ counts,
                                                    int* __restrict__ partials, int n) {
    __shared__ int s[256];
    int i = blockIdx.x * 256 + threadIdx.x;
    int v = (i < n) ? counts[i] : 0;
    s[threadIdx.x] = v;
    __syncthreads();
    for (int off = 128; off > 0; off >>= 1) {
        if (threadIdx.x < off) s[threadIdx.x] += s[threadIdx.x + off];
        __syncthreads();
    }
    if (threadIdx.x == 0) partials[blockIdx.x] = s[0];
}

// scan3 with inline base reduction (no scan2 dispatch), nb<=256
__global__ __launch_bounds__(256) void scan3_kernel(const int* __restrict__ counts,
                                                    const int* __restrict__ partials,
                                                    int* __restrict__ row_ptr,
                                                    int* __restrict__ cursor, int n, int nb) {
    __shared__ int s[256];
    __shared__ int base_sh;
    int t = threadIdx.x;
    int pv = (t < (int)blockIdx.x && t < nb) ? partials[t] : 0;
    s[t] = pv;
    __syncthreads();
    for (int off = 128; off > 0; off >>= 1) {
        if (t < off) s[t] += s[t + off];
        __syncthreads();
    }
    if (t == 0) base_sh = s[0];
    __syncthreads();
    int base = base_sh;
    int i = blockIdx.x * 256 + t;
    int v = (i < n) ? counts[i] : 0;
    __syncthreads();
    s[t] = v;
    __syncthreads();
    for (int off = 1; off < 256; off <<= 1) {
        int nv = (t >= off) ? s[t - off] : 0;
        __syncthreads();
        s[t] += nv;
        __syncthreads();
    }
    if (i < n) {
        int ex = base + s[t] - v;   // exclusive
        row_ptr[i] = ex;
        cursor[i] = ex;
    }
}

__global__ __launch_bounds__(256) void scatter_kernel(const int* __restrict__ src,
                                                      const int* __restrict__ dst,
                                                      int* __restrict__ cursor,
                                                      int* __restrict__ esrc, int E) {
    int i = blockIdx.x * 256 + threadIdx.x;
    if (i < E) {
        int p = atomicAdd(&cursor[dst[i]], 1);
        esrc[p] = src[i];
    }
}

// ------------------------------------------------------------- aggregation
// (R14-proven) 2 nodes/wave, 32 lanes x 4 ch, all terms (incl. self) from
// the single bf16 plane. fp32 accumulate -> bf16 plane out.
__global__ __launch_bounds__(256) void agg_kernel(
    const ushort* __restrict__ phi,
    const int* __restrict__ rp, const int* __restrict__ esrc,
    ushort* __restrict__ ohi, int n) {
    int wid  = (blockIdx.x * 256 + threadIdx.x) >> 6;
    int lane = threadIdx.x & 63;
    int node = wid * 2 + (lane >> 5);
    int q = lane & 31;
    if (node >= n) return;
    const ushort4* xh = (const ushort4*)phi;
    ushort4 sh = xh[(size_t)node * 32 + q];
    float4 acc;
    acc.x = b2f(sh.x); acc.y = b2f(sh.y); acc.z = b2f(sh.z); acc.w = b2f(sh.w);
    int beg = rp[node], end = rp[node + 1];
    int e = beg;
    for (; e + 8 <= end; e += 8) {
        int i0 = esrc[e],     i1 = esrc[e + 1], i2 = esrc[e + 2], i3 = esrc[e + 3];
        int i4 = esrc[e + 4], i5 = esrc[e + 5], i6 = esrc[e + 6], i7 = esrc[e + 7];
        ushort4 v0 = xh[(size_t)i0 * 32 + q];
        ushort4 v1 = xh[(size_t)i1 * 32 + q];
        ushort4 v2 = xh[(size_t)i2 * 32 + q];
        ushort4 v3 = xh[(size_t)i3 * 32 + q];
        ushort4 v4 = xh[(size_t)i4 * 32 + q];
        ushort4 v5 = xh[(size_t)i5 * 32 + q];
        ushort4 v6 = xh[(size_t)i6 * 32 + q];
        ushort4 v7 = xh[(size_t)i7 * 32 + q];
        acc.x += ((b2f(v0.x) + b2f(v1.x)) + (b2f(v2.x) + b2f(v3.x))) +
                 ((b2f(v4.x) + b2f(v5.x)) + (b2f(v6.x) + b2f(v7.x)));
        acc.y += ((b2f(v0.y) + b2f(v1.y)) + (b2f(v2.y) + b2f(v3.y))) +
                 ((b2f(v4.y) + b2f(v5.y)) + (b2f(v6.y) + b2f(v7.y)));
        acc.z += ((b2f(v0.z) + b2f(v1.z)) + (b2f(v2.z) + b2f(v3.z))) +
                 ((b2f(v4.z) + b2f(v5.z)) + (b2f(v6.z) + b2f(v7.z)));
        acc.w += ((b2f(v0.w) + b2f(v1.w)) + (b2f(v2.w) + b2f(v3.w))) +
                 ((b2f(v4.w) + b2f(v5.w)) + (b2f(v6.w) + b2f(v7.w)));
    }
    for (; e + 2 <= end; e += 2) {
        int i0 = esrc[e], i1 = esrc[e + 1];
        ushort4 v0 = xh[(size_t)i0 * 32 + q];
        ushort4 v1 = xh[(size_t)i1 * 32 + q];
        acc.x += b2f(v0.x) + b2f(v1.x); acc.y += b2f(v0.y) + b2f(v1.y);
        acc.z += b2f(v0.z) + b2f(v1.z); acc.w += b2f(v0.w) + b2f(v1.w);
    }
    for (; e < end; e++) {
        ushort4 v = xh[(size_t)esrc[e] * 32 + q];
        acc.x += b2f(v.x); acc.y += b2f(v.y); acc.z += b2f(v.z); acc.w += b2f(v.w);
    }
    ushort4 hh = {f2b(acc.x), f2b(acc.y), f2b(acc.z), f2b(acc.w)};
    *(ushort4*)(ohi + (size_t)node * 128 + q * 4) = hh;
}

// --------------------------------------------------------------- fused MLP
// C = act( BN_ReLU( A@W1 ) @ W2 ), 64-row tile x 128 threads (2 waves),
// grid 782 (R14's 391x256 left 1.53 blocks/CU — makespan set by 2-block
// CUs). PER-WAVE SHAPE UNCHANGED from proven R14: 64x64 wave tile, 4x4
// frags, 32 MFMA/kb (R12 showed halving THAT is what regresses). Both waves
// share A frags; wave wv owns col-half wv. bf16 single-plane activations;
// W hi/lo -> 2 MFMA terms. LDS 17.4KB. Fused mean-pool epilogue.
template <bool RELU_OUT, bool WRITE_PLANES>
__global__ __launch_bounds__(128) void mlp_kernel(
    const ushort* __restrict__ Ah,
    const ushort* __restrict__ W1hi, const ushort* __restrict__ W1lo,
    const ushort* __restrict__ W2hi, const ushort* __restrict__ W2lo,
    const float* __restrict__ b1, const float* __restrict__ gm,
    const float* __restrict__ bt, const float* __restrict__ rm,
    const float* __restrict__ rv, const float* __restrict__ b2,
    ushort* __restrict__ Ch,
    const int* __restrict__ batch, float* __restrict__ pooled, int poff, int M) {
    __shared__ __align__(16) ushort smem[64 * 136];   // 17408 B
    __shared__ int bsm[64];
    // A dbuf: smem[buf*4096 + m*32 + k]  (8192 ushorts, fits in smem)
    // H / P:  smem[row*136 + col]
    const int t = threadIdx.x;            // 0..127
    const int lane = t & 63;
    const int wv = t >> 6;                // col half
    const int row0 = blockIdx.x * 64;
    const int g = lane >> 4, c = lane & 15;

    if (t < 64) bsm[t] = (row0 + t < M) ? batch[row0 + t] : -1;

    // staging: 256 16B-segs per kb; thread owns segs t and t+128
    const int m0 = t >> 2, k80 = (t & 3) * 8;
    const int m1 = m0 + 32;
    int r0 = row0 + m0; if (r0 >= M) r0 = M - 1;
    int r1 = row0 + m1; if (r1 >= M) r1 = M - 1;
    const size_t ga0 = (size_t)r0 * 128 + k80;
    const size_t ga1 = (size_t)r1 * 128 + k80;
    const int la0 = m0 * 32 + k80, la1 = m1 * 32 + k80;

    f32x4 acc[4][4];
#pragma unroll
    for (int i = 0; i < 4; i++)
#pragma unroll
        for (int j = 0; j < 4; j++) acc[i][j] = (f32x4){0.f, 0.f, 0.f, 0.f};

    uint4 ph0 = *(const uint4*)(Ah + ga0);
    uint4 ph1 = *(const uint4*)(Ah + ga1);
    *(uint4*)&smem[la0] = ph0;
    *(uint4*)&smem[la1] = ph1;
    __syncthreads();

    // ---------------- phase 1: A @ W1 (2 terms)
    int cur = 0;
    for (int kb = 0; kb < 4; kb++) {
        bf16x8 bh[4], bl[4];
#pragma unroll
        for (int ct = 0; ct < 4; ct++) {
            const size_t wo = (size_t)(wv * 64 + ct * 16 + c) * 128 + kb * 32 + g * 8;
            bh[ct] = *(const bf16x8*)(W1hi + wo);
            bl[ct] = *(const bf16x8*)(W1lo + wo);
        }
        if (kb < 3) {
            const size_t o = (size_t)(kb + 1) * 32;
            ph0 = *(const uint4*)(Ah + ga0 + o);
            ph1 = *(const uint4*)(Ah + ga1 + o);
        }
        bf16x8 ah[4];
#pragma unroll
        for (int rt = 0; rt < 4; rt++) {
            int off = cur * 4096 + (rt * 16 + c) * 32 + g * 8;
            ah[rt] = *(bf16x8*)&smem[off];
        }
#pragma unroll
        for (int rt = 0; rt < 4; rt++)
#pragma unroll
            for (int ct = 0; ct < 4; ct++) {
                acc[rt][ct] = __builtin_amdgcn_mfma_f32_16x16x32_bf16(ah[rt], bh[ct], acc[rt][ct], 0, 0, 0);
                acc[rt][ct] = __builtin_amdgcn_mfma_f32_16x16x32_bf16(ah[rt], bl[ct], acc[rt][ct], 0, 0, 0);
            }
        if (kb < 3) {
            *(uint4*)&smem[(cur ^ 1) * 4096 + la0] = ph0;
            *(uint4*)&smem[(cur ^ 1) * 4096 + la1] = ph1;
        }
        __syncthreads();   // final iter: all A reads done -> H may overwrite
        cur ^= 1;
    }

    // ---------------- BN + ReLU -> H (bf16)
    {
        float cs[4], ca[4];
#pragma unroll
        for (int ct = 0; ct < 4; ct++) {
            int n = wv * 64 + ct * 16 + c;
            float s = gm[n] * rsqrtf(rv[n] + BN_EPS);
            cs[ct] = s;
            ca[ct] = (b1[n] - rm[n]) * s + bt[n];
        }
#pragma unroll
        for (int rt = 0; rt < 4; rt++)
#pragma unroll
            for (int r = 0; r < 4; r++) {
                int row = rt * 16 + g * 4 + r;
#pragma unroll
                for (int ct = 0; ct < 4; ct++) {
                    int col = wv * 64 + ct * 16 + c;
                    float v = fmaxf(acc[rt][ct][r] * cs[ct] + ca[ct], 0.f);
                    smem[row * 136 + col] = f2b(v);
                }
            }
    }
    __syncthreads();

    // ---------------- phase 2: H @ W2 (2 terms)
#pragma unroll
    for (int i = 0; i < 4; i++)
#pragma unroll
        for (int j = 0; j < 4; j++) acc[i][j] = (f32x4){0.f, 0.f, 0.f, 0.f};

    for (int kb = 0; kb < 4; kb++) {
        bf16x8 bh[4], bl[4];
#pragma unroll
        for (int ct = 0; ct < 4; ct++) {
            const size_t wo = (size_t)(wv * 64 + ct * 16 + c) * 128 + kb * 32 + g * 8;
            bh[ct] = *(const bf16x8*)(W2hi + wo);
            bl[ct] = *(const bf16x8*)(W2lo + wo);
        }
        bf16x8 ah[4];
#pragma unroll
        for (int rt = 0; rt < 4; rt++) {
            int off = (rt * 16 + c) * 136 + kb * 32 + g * 8;
            ah[rt] = *(bf16x8*)&smem[off];
        }
#pragma unroll
        for (int rt = 0; rt < 4; rt++)
#pragma unroll
            for (int ct = 0; ct < 4; ct++) {
                acc[rt][ct] = __builtin_amdgcn_mfma_f32_16x16x32_bf16(ah[rt], bh[ct], acc[rt][ct], 0, 0, 0);
                acc[rt][ct] = __builtin_amdgcn_mfma_f32_16x16x32_bf16(ah[rt], bl[ct], acc[rt][ct], 0, 0, 0);
            }
    }
    __syncthreads();   // all H reads done -> P may overwrite smem

    // ---------------- epilogue: +b2 (,ReLU) -> bf16 plane + LDS P (bf16)
    {
        float ca2[4];
#pragma unroll
        for (int ct = 0; ct < 4; ct++) ca2[ct] = b2[wv * 64 + ct * 16 + c];
#pragma unroll
        for (int rt = 0; rt < 4; rt++)
#pragma unroll
            for (int r = 0; r < 4; r++) {
                int rl = rt * 16 + g * 4 + r;
                int row = row0 + rl;
                bool valid = row < M;
#pragma unroll
                for (int ct = 0; ct < 4; ct++) {
                    int col = wv * 64 + ct * 16 + c;
                    float v = acc[rt][ct][r] + ca2[ct];
                    if (RELU_OUT) v = fmaxf(v, 0.f);
                    ushort hh = f2b(valid ? v : 0.f);
                    smem[rl * 136 + col] = hh;
                    if (WRITE_PLANES && valid) Ch[(size_t)row * 128 + col] = hh;
                }
            }
    }
    __syncthreads();

    // ---------------- fused mean-pool contribution (batch is sorted)
    {
        int col = t;              // 0..127
        int gcur = bsm[0];
        float accp = 0.f;
#pragma unroll 8
        for (int r = 0; r < 64; r++) {
            int gg = bsm[r];
            if (gg != gcur) {     // block-uniform branch (sorted batch)
                if (gcur >= 0) atomicAdd(&pooled[gcur * 384 + poff + col], accp);
                accp = 0.f;
                gcur = gg;
            }
            accp += b2f(smem[r * 136 + col]);
        }
        if (gcur >= 0) atomicAdd(&pooled[gcur * 384 + poff + col], accp);
    }
}

// ------------------------------------------------------------------- final
__global__ __launch_bounds__(128) void final_kernel(const float* __restrict__ pooled,
                                                    const int* __restrict__ batch,
                                                    const float* __restrict__ W,
                                                    const float* __restrict__ b,
                                                    float* __restrict__ out, int n) {
    __shared__ float ps[384];
    int gph = blockIdx.x, t = threadIdx.x;
    int lo1 = 0, hi1 = n;
    while (lo1 < hi1) { int mid = (lo1 + hi1) >> 1; if (batch[mid] < gph) lo1 = mid + 1; else hi1 = mid; }
    int start = lo1;
    int lo2 = start, hi2 = n;
    while (lo2 < hi2) { int mid = (lo2 + hi2) >> 1; if (batch[mid] < gph + 1) lo2 = mid + 1; else hi2 = mid; }
    int cnt = lo2 - start;
    float inv = 1.f / (float)(cnt > 0 ? cnt : 1);
    for (int i = t; i < 384; i += 128) ps[i] = pooled[gph * 384 + i] * inv;
    __syncthreads();
    float acc = b[t];
#pragma unroll 8
    for (int k = 0; k < 384; k++) acc += ps[k] * W[k * 128 + t];
    out[gph * 128 + t] = acc;
}

// ------------------------------------------------------------------ launch
extern "C" void kernel_launch(void* const* d_in, const int* in_sizes, int n_in,
                              void* d_out, int out_size, void* d_ws, size_t ws_size,
                              hipStream_t stream) {
    const float* x     = (const float*)d_in[0];
    const int*   edge  = (const int*)d_in[1];
    const int*   batch = (const int*)d_in[2];
    const float* p[32];
    for (int i = 0; i < n_in && i < 32; i++) p[i] = (const float*)d_in[i];
    const float* lin_W = p[27];
    const float* lin_b = p[28];

    char* w = (char*)d_ws;
    auto alloc = [&](size_t bytes) { void* r = (void*)w; w += (bytes + 255) & ~(size_t)255; return r; };
    const size_t PL = (size_t)NNODES * 128;
    ushort* thi   = (ushort*)alloc(PL * 2);   // agg out plane
    ushort* xh0   = (ushort*)alloc(PL * 2);   // bf16(x); dead after agg L1
    ushort* p1h   = (ushort*)alloc(PL * 2);
    ushort* p2h   = xh0;                      // alias: xh0 dead before mlp L2 writes
    float* pooled = (float*)alloc((size_t)NGRAPHS * 384 * 4);
    int* counts   = (int*)alloc((size_t)NNODES * 4);
    int* cursor   = (int*)alloc((size_t)NNODES * 4);
    int* row_ptr  = (int*)alloc((size_t)(NNODES + 1) * 4);
    int* esrc     = (int*)alloc((size_t)NEDGES * 4);
    int* partials = (int*)alloc(256 * 4);
    ushort* wt_hi = (ushort*)alloc((size_t)6 * 16384 * 2);
    ushort* wt_lo = (ushort*)alloc((size_t)6 * 16384 * 2);

    const int* src = edge;
    const int* dst = edge + NEDGES;

    // --- prep: x->bf16, zero pooled/counts, row_ptr[N], wsplit (1 dispatch)
    prep_kernel<<<3609, 256, 0, stream>>>(x, xh0, pooled, counts, row_ptr,
                                          p[3], p[9], p[11], p[17], p[19], p[25],
                                          wt_hi, wt_lo);

    // --- CSR build: 4 dispatches
    int nb = (NNODES + 255) / 256;  // 196
    hist_kernel<<<(NEDGES + 255) / 256, 256, 0, stream>>>(dst, counts, NEDGES);
    scan1_kernel<<<nb, 256, 0, stream>>>(counts, partials, NNODES);
    scan3_kernel<<<nb, 256, 0, stream>>>(counts, partials, row_ptr, cursor, NNODES, nb);
    scatter_kernel<<<(NEDGES + 255) / 256, 256, 0, stream>>>(src, dst, cursor, esrc, NEDGES);

    // --- 3 GIN layers (mlp fuses the mean-pool contribution)
    int mlp_grid = (NNODES + 63) / 64;              // 782
    int agg_grid = (NNODES / 2 * 64 + 255) / 256;   // 6250

    // layer 1 (self from bf16 plane — same rounding class as neighbors)
    agg_kernel<<<agg_grid, 256, 0, stream>>>(xh0, row_ptr, esrc, thi, NNODES);
    mlp_kernel<true, true><<<mlp_grid, 128, 0, stream>>>(thi,
        wt_hi + 0 * 16384, wt_lo + 0 * 16384, wt_hi + 1 * 16384, wt_lo + 1 * 16384,
        p[4], p[5], p[6], p[7], p[8], p[10], p1h, batch, pooled, 0, NNODES);
    // layer 2
    agg_kernel<<<agg_grid, 256, 0, stream>>>(p1h, row_ptr, esrc, thi, NNODES);
    mlp_kernel<true, true><<<mlp_grid, 128, 0, stream>>>(thi,
        wt_hi + 2 * 16384, wt_lo + 2 * 16384, wt_hi + 3 * 16384, wt_lo + 3 * 16384,
        p[12], p[13], p[14], p[15], p[16], p[18], p2h, batch, pooled, 128, NNODES);
    // layer 3 (no relu, no plane writes — pool-only output)
    agg_kernel<<<agg_grid, 256, 0, stream>>>(p2h, row_ptr, esrc, thi, NNODES);
    mlp_kernel<false, false><<<mlp_grid, 128, 0, stream>>>(thi,
        wt_hi + 4 * 16384, wt_lo + 4 * 16384, wt_hi + 5 * 16384, wt_lo + 5 * 16384,
        p[20], p[21], p[22], p[23], p[24], p[26], nullptr, batch, pooled, 256, NNODES);

    // --- final linear on mean-pooled JK-concat
    final_kernel<<<NGRAPHS, 128, 0, stream>>>(pooled, batch, lin_W, lin_b,
                                              (float*)d_out, NNODES);
}